// Round 1
// baseline (637.588 us; speedup 1.0000x reference)
//
#include <hip/hip_runtime.h>

typedef unsigned short ushort_t;
typedef __bf16 bf16x8 __attribute__((ext_vector_type(8)));
typedef float f32x4 __attribute__((ext_vector_type(4)));

#define S_LEN 2048
#define DMODEL 2048
#define NH 16
#define HDIM 128
#define BATCH 2
#define M_ROWS (BATCH * S_LEN) // 4096

__device__ __forceinline__ ushort_t f2bf(float f) {
    union { float f; unsigned u; } v; v.f = f;
    unsigned r = (v.u + 0x7fffu + ((v.u >> 16) & 1u)) >> 16;
    return (ushort_t)r;
}
__device__ __forceinline__ float bf2f(ushort_t u) {
    union { unsigned u; float f; } v; v.u = ((unsigned)u) << 16;
    return v.f;
}

__device__ __forceinline__ void async16(const void* g, void* l) {
    __builtin_amdgcn_global_load_lds(
        (const __attribute__((address_space(1))) void*)g,
        (__attribute__((address_space(3))) void*)l, 16, 0, 0);
}

// ---------------- fp32 -> bf16 (4 elems/thread) ----------------
__global__ void cvt_bf16(const float* __restrict__ in, ushort_t* __restrict__ out, int n4) {
    int i = blockIdx.x * blockDim.x + threadIdx.x;
    if (i >= n4) return;
    float4 f = ((const float4*)in)[i];
    ushort4 u;
    u.x = f2bf(f.x); u.y = f2bf(f.y); u.z = f2bf(f.z); u.w = f2bf(f.w);
    ((ushort4*)out)[i] = u;
}

// ---------------- RoPE tables [S][64] ----------------
__global__ void rope_tables(float* __restrict__ cosT, float* __restrict__ sinT) {
    int i = blockIdx.x * blockDim.x + threadIdx.x; // 2048*64
    int s = i >> 6, f = i & 63;
    float inv = powf(10000.0f, -(float)(2 * f) / 128.0f);
    float ang = (float)s * inv;
    cosT[i] = cosf(ang);
    sinT[i] = sinf(ang);
}

// ---------------- RoPE in-place on Q and K ([BH][S][HD] bf16) ----------------
__global__ void rope_inplace(ushort_t* __restrict__ Q, ushort_t* __restrict__ K,
                             const float* __restrict__ cosT, const float* __restrict__ sinT) {
    long i = (long)blockIdx.x * blockDim.x + threadIdx.x; // 32*2048*64
    int f = (int)(i & 63);
    long t = i >> 6;
    int s = (int)(t & (S_LEN - 1));
    int bh = (int)(t >> 11);
    long base = ((long)bh * S_LEN + s) * HDIM;
    float c = cosT[s * 64 + f], sn = sinT[s * 64 + f];
    float a0 = bf2f(Q[base + f]), a1 = bf2f(Q[base + 64 + f]);
    Q[base + f]      = f2bf(a0 * c - a1 * sn);
    Q[base + 64 + f] = f2bf(a1 * c + a0 * sn);
    float b0 = bf2f(K[base + f]), b1 = bf2f(K[base + 64 + f]);
    K[base + f]      = f2bf(b0 * c - b1 * sn);
    K[base + 64 + f] = f2bf(b1 * c + b0 * sn);
}

// ---------------- GEMM: C[i][j] = sum_k A[i][k] * B[j][k]  (both row-major [.,K]) ----
// 128x128 tile, BK=32, 256 threads (4 waves, 2x2 of 64x64), m97-style structure.
// EPI: 0 = scatter bf16 to [B,H,S,HD]; 1 = scatter bf16 to [B,H,HD,S]; 2 = fp32 row-major.
template <int EPI>
__global__ __launch_bounds__(256) void gemm_bt(
    const ushort_t* __restrict__ A, const ushort_t* __restrict__ Bm,
    void* __restrict__ Cout, int M, int N, int K) {
    __shared__ __align__(16) ushort_t As[128 * 32];
    __shared__ __align__(16) ushort_t Bs[128 * 32];
    const int tid = threadIdx.x;
    const int lane = tid & 63;
    const int w = tid >> 6;
    const int wr = (w >> 1) * 64, wc = (w & 1) * 64;
    const int fr = lane & 15, fk = (lane >> 4) * 8;
    const int brow = blockIdx.x * 128, bcol = blockIdx.y * 128;

    f32x4 acc[4][4];
#pragma unroll
    for (int i = 0; i < 4; i++)
#pragma unroll
        for (int j = 0; j < 4; j++) acc[i][j] = (f32x4){0.f, 0.f, 0.f, 0.f};

    for (int k0 = 0; k0 < K; k0 += 32) {
#pragma unroll
        for (int hh = 0; hh < 2; hh++) {
            int c = hh * 256 + tid;
            int row = c >> 2, colb = (c & 3) * 8;
            async16(&A[(long)(brow + row) * K + k0 + colb], &As[c * 8]);
            async16(&Bm[(long)(bcol + row) * K + k0 + colb], &Bs[c * 8]);
        }
        __syncthreads();
        bf16x8 af[4], bfr[4];
#pragma unroll
        for (int i = 0; i < 4; i++) {
            af[i]  = *(const bf16x8*)&As[(wr + i * 16 + fr) * 32 + fk];
            bfr[i] = *(const bf16x8*)&Bs[(wc + i * 16 + fr) * 32 + fk];
        }
#pragma unroll
        for (int i = 0; i < 4; i++)
#pragma unroll
            for (int j = 0; j < 4; j++)
                acc[i][j] = __builtin_amdgcn_mfma_f32_16x16x32_bf16(af[i], bfr[j], acc[i][j], 0, 0, 0);
        __syncthreads();
    }

#pragma unroll
    for (int i = 0; i < 4; i++)
#pragma unroll
        for (int j = 0; j < 4; j++)
#pragma unroll
            for (int r = 0; r < 4; r++) {
                int row = brow + wr + i * 16 + ((lane >> 4) << 2) + r;
                int col = bcol + wc + j * 16 + fr;
                float v = acc[i][j][r];
                if constexpr (EPI == 0) {
                    int b = row >> 11, s = row & (S_LEN - 1);
                    int h = col >> 7, hd = col & 127;
                    ((ushort_t*)Cout)[(((long)(b * NH + h) * S_LEN) + s) * HDIM + hd] = f2bf(v);
                } else if constexpr (EPI == 1) {
                    int b = row >> 11, s = row & (S_LEN - 1);
                    int h = col >> 7, hd = col & 127;
                    ((ushort_t*)Cout)[(((long)(b * NH + h) * HDIM) + hd) * S_LEN + s] = f2bf(v);
                } else {
                    ((float*)Cout)[(long)row * N + col] = v;
                }
            }
}

// ---------------- Flash attention, causal, 1 wave per 16 q-rows ----------------
// Q,K: [BH][S][HD] bf16 (post-RoPE), Vt: [BH][HD][S] bf16, ctx out: [B][S][D] bf16
__global__ __launch_bounds__(64) void attn_fwd(
    const ushort_t* __restrict__ Q, const ushort_t* __restrict__ K,
    const ushort_t* __restrict__ Vt, ushort_t* __restrict__ ctx) {
    const int lane = threadIdx.x;
    const int fr = lane & 15, fk = (lane >> 4) * 8;
    const int q0 = blockIdx.x * 16;
    const int bh = blockIdx.y;
    const int b = bh >> 4, h = bh & 15;

    const ushort_t* Qb = Q + (long)bh * S_LEN * HDIM;
    const ushort_t* Kb = K + (long)bh * S_LEN * HDIM;
    const ushort_t* Vb = Vt + (long)bh * HDIM * S_LEN;

    bf16x8 qf[4];
#pragma unroll
    for (int t = 0; t < 4; t++)
        qf[t] = *(const bf16x8*)&Qb[(long)(q0 + fr) * HDIM + t * 32 + fk];

    f32x4 o[8];
#pragma unroll
    for (int i = 0; i < 8; i++) o[i] = (f32x4){0.f, 0.f, 0.f, 0.f};
    float mrun[4] = {-1e30f, -1e30f, -1e30f, -1e30f};
    float lrun[4] = {0.f, 0.f, 0.f, 0.f};

    __shared__ __align__(16) ushort_t Pl[16 * 64];
    const float scale = 0.08838834764831845f; // 1/sqrt(128)
    const int rbase = q0 + ((lane >> 4) << 2);
    const int kv_end = q0 + 16;

    for (int kv0 = 0; kv0 < kv_end; kv0 += 64) {
        f32x4 sf[4];
#pragma unroll
        for (int c = 0; c < 4; c++) sf[c] = (f32x4){0.f, 0.f, 0.f, 0.f};
#pragma unroll
        for (int c = 0; c < 4; c++) {
#pragma unroll
            for (int t = 0; t < 4; t++) {
                bf16x8 kb = *(const bf16x8*)&Kb[(long)(kv0 + c * 16 + fr) * HDIM + t * 32 + fk];
                sf[c] = __builtin_amdgcn_mfma_f32_16x16x32_bf16(qf[t], kb, sf[c], 0, 0, 0);
            }
        }
        // scale + causal mask
#pragma unroll
        for (int c = 0; c < 4; c++) {
            int col = kv0 + c * 16 + fr;
#pragma unroll
            for (int r = 0; r < 4; r++)
                sf[c][r] = (col <= rbase + r) ? sf[c][r] * scale : -1e30f;
        }
        // online softmax (per row r, reduce across 16-lane group)
#pragma unroll
        for (int r = 0; r < 4; r++) {
            float vmax = fmaxf(fmaxf(sf[0][r], sf[1][r]), fmaxf(sf[2][r], sf[3][r]));
#pragma unroll
            for (int off = 8; off; off >>= 1) vmax = fmaxf(vmax, __shfl_xor(vmax, off, 16));
            float nm = fmaxf(mrun[r], vmax);
            float alpha = __expf(mrun[r] - nm);
            float rs = 0.f;
#pragma unroll
            for (int c = 0; c < 4; c++) {
                float p = __expf(sf[c][r] - nm);
                sf[c][r] = p;
                rs += p;
            }
#pragma unroll
            for (int off = 8; off; off >>= 1) rs += __shfl_xor(rs, off, 16);
            lrun[r] = lrun[r] * alpha + rs;
            mrun[r] = nm;
#pragma unroll
            for (int dt = 0; dt < 8; dt++) o[dt][r] *= alpha;
        }
        // P -> LDS (C-layout -> A-layout round trip)
        __syncthreads();
#pragma unroll
        for (int c = 0; c < 4; c++)
#pragma unroll
            for (int r = 0; r < 4; r++)
                Pl[(((lane >> 4) << 2) + r) * 64 + c * 16 + fr] = f2bf(sf[c][r]);
        __syncthreads();
        bf16x8 pa[2];
        pa[0] = *(const bf16x8*)&Pl[fr * 64 + fk];
        pa[1] = *(const bf16x8*)&Pl[fr * 64 + 32 + fk];
#pragma unroll
        for (int dt = 0; dt < 8; dt++) {
#pragma unroll
            for (int hh = 0; hh < 2; hh++) {
                bf16x8 vb = *(const bf16x8*)&Vb[(long)(dt * 16 + fr) * S_LEN + kv0 + hh * 32 + fk];
                o[dt] = __builtin_amdgcn_mfma_f32_16x16x32_bf16(pa[hh], vb, o[dt], 0, 0, 0);
            }
        }
    }

    long obase = ((long)b * S_LEN) * DMODEL + (long)h * HDIM;
#pragma unroll
    for (int dt = 0; dt < 8; dt++)
#pragma unroll
        for (int r = 0; r < 4; r++) {
            int srow = q0 + ((lane >> 4) << 2) + r;
            ctx[obase + (long)srow * DMODEL + dt * 16 + fr] = f2bf(o[dt][r] / lrun[r]);
        }
}

extern "C" void kernel_launch(void* const* d_in, const int* in_sizes, int n_in,
                              void* d_out, int out_size, void* d_ws, size_t ws_size,
                              hipStream_t stream) {
    const float* hs = (const float*)d_in[0];
    const float* Wq = (const float*)d_in[1];
    const float* Wk = (const float*)d_in[2];
    const float* Wv = (const float*)d_in[3];
    const float* Wo = (const float*)d_in[4];
    float* out = (float*)d_out;

    size_t off = 0;
    char* wsb = (char*)d_ws;
    auto carve = [&](size_t bytes) { void* p = wsb + off; off += bytes; return p; };

    ushort_t* Xb   = (ushort_t*)carve((size_t)M_ROWS * DMODEL * 2);
    ushort_t* Wqb  = (ushort_t*)carve((size_t)DMODEL * DMODEL * 2);
    ushort_t* Wkb  = (ushort_t*)carve((size_t)DMODEL * DMODEL * 2);
    ushort_t* Wvb  = (ushort_t*)carve((size_t)DMODEL * DMODEL * 2);
    ushort_t* Wob  = (ushort_t*)carve((size_t)DMODEL * DMODEL * 2);
    ushort_t* Qb   = (ushort_t*)carve((size_t)BATCH * NH * S_LEN * HDIM * 2);
    ushort_t* Kb   = (ushort_t*)carve((size_t)BATCH * NH * S_LEN * HDIM * 2);
    ushort_t* Vtb  = (ushort_t*)carve((size_t)BATCH * NH * S_LEN * HDIM * 2);
    ushort_t* ctxb = (ushort_t*)carve((size_t)M_ROWS * DMODEL * 2);
    float* cosT    = (float*)carve((size_t)S_LEN * 64 * 4);
    float* sinT    = (float*)carve((size_t)S_LEN * 64 * 4);

    const int nX = M_ROWS * DMODEL;   // 8388608
    const int nW = DMODEL * DMODEL;   // 4194304

    cvt_bf16<<<(nX / 4) / 256, 256, 0, stream>>>(hs, Xb, nX / 4);
    cvt_bf16<<<(nW / 4) / 256, 256, 0, stream>>>(Wq, Wqb, nW / 4);
    cvt_bf16<<<(nW / 4) / 256, 256, 0, stream>>>(Wk, Wkb, nW / 4);
    cvt_bf16<<<(nW / 4) / 256, 256, 0, stream>>>(Wv, Wvb, nW / 4);
    cvt_bf16<<<(nW / 4) / 256, 256, 0, stream>>>(Wo, Wob, nW / 4);
    rope_tables<<<(S_LEN * 64) / 256, 256, 0, stream>>>(cosT, sinT);

    dim3 gg(M_ROWS / 128, DMODEL / 128);
    gemm_bt<0><<<gg, 256, 0, stream>>>(Xb, Wqb, Qb, M_ROWS, DMODEL, DMODEL);
    gemm_bt<0><<<gg, 256, 0, stream>>>(Xb, Wkb, Kb, M_ROWS, DMODEL, DMODEL);
    gemm_bt<1><<<gg, 256, 0, stream>>>(Xb, Wvb, Vtb, M_ROWS, DMODEL, DMODEL);

    rope_inplace<<<(BATCH * NH * S_LEN * 64) / 256, 256, 0, stream>>>(Qb, Kb, cosT, sinT);

    attn_fwd<<<dim3(S_LEN / 16, BATCH * NH), 64, 0, stream>>>(Qb, Kb, Vtb, ctxb);

    gemm_bt<2><<<gg, 256, 0, stream>>>(ctxb, Wob, out, M_ROWS, DMODEL, DMODEL);
}

// Round 2
// 495.177 us; speedup vs baseline: 1.2876x; 1.2876x over previous
//
#include <hip/hip_runtime.h>

typedef unsigned short ushort_t;
typedef __bf16 bf16x8 __attribute__((ext_vector_type(8)));
typedef float f32x4 __attribute__((ext_vector_type(4)));

#define S_LEN 2048
#define DMODEL 2048
#define NH 16
#define HDIM 128
#define BATCH 2
#define M_ROWS (BATCH * S_LEN) // 4096

__device__ __forceinline__ ushort_t f2bf(float f) {
    union { float f; unsigned u; } v; v.f = f;
    unsigned r = (v.u + 0x7fffu + ((v.u >> 16) & 1u)) >> 16;
    return (ushort_t)r;
}
__device__ __forceinline__ float bf2f(ushort_t u) {
    union { unsigned u; float f; } v; v.u = ((unsigned)u) << 16;
    return v.f;
}

__device__ __forceinline__ void async16(const void* g, void* l) {
    __builtin_amdgcn_global_load_lds(
        (const __attribute__((address_space(1))) void*)g,
        (__attribute__((address_space(3))) void*)l, 16, 0, 0);
}

// ---------------- fp32 -> bf16 (4 elems/thread) ----------------
__global__ void cvt_bf16(const float* __restrict__ in, ushort_t* __restrict__ out, int n4) {
    int i = blockIdx.x * blockDim.x + threadIdx.x;
    if (i >= n4) return;
    float4 f = ((const float4*)in)[i];
    ushort4 u;
    u.x = f2bf(f.x); u.y = f2bf(f.y); u.z = f2bf(f.z); u.w = f2bf(f.w);
    ((ushort4*)out)[i] = u;
}

// ---------------- RoPE tables [S][64] ----------------
__global__ void rope_tables(float* __restrict__ cosT, float* __restrict__ sinT) {
    int i = blockIdx.x * blockDim.x + threadIdx.x; // 2048*64
    int s = i >> 6, f = i & 63;
    float inv = powf(10000.0f, -(float)(2 * f) / 128.0f);
    float ang = (float)s * inv;
    cosT[i] = cosf(ang);
    sinT[i] = sinf(ang);
}

// ---------------- RoPE in-place on Q and K ([BH][S][HD] bf16) ----------------
__global__ void rope_inplace(ushort_t* __restrict__ Q, ushort_t* __restrict__ K,
                             const float* __restrict__ cosT, const float* __restrict__ sinT) {
    long i = (long)blockIdx.x * blockDim.x + threadIdx.x; // 32*2048*64
    int f = (int)(i & 63);
    long t = i >> 6;
    int s = (int)(t & (S_LEN - 1));
    int bh = (int)(t >> 11);
    long base = ((long)bh * S_LEN + s) * HDIM;
    float c = cosT[s * 64 + f], sn = sinT[s * 64 + f];
    float a0 = bf2f(Q[base + f]), a1 = bf2f(Q[base + 64 + f]);
    Q[base + f]      = f2bf(a0 * c - a1 * sn);
    Q[base + 64 + f] = f2bf(a1 * c + a0 * sn);
    float b0 = bf2f(K[base + f]), b1 = bf2f(K[base + 64 + f]);
    K[base + f]      = f2bf(b0 * c - b1 * sn);
    K[base + 64 + f] = f2bf(b1 * c + b0 * sn);
}

// ---------------- GEMM: C[i][j] = sum_k A[i][k] * B[j][k]  (both row-major [.,K]) ----
// 128x128 tile, BK=32, 256 threads (4 waves, 2x2 of 64x64), m97-style structure.
// EPI: 0 = scatter bf16 to [B,H,S,HD]; 1 = scatter bf16 to [B,H,HD,S]; 2 = fp32 row-major.
template <int EPI>
__global__ __launch_bounds__(256) void gemm_bt(
    const ushort_t* __restrict__ A, const ushort_t* __restrict__ Bm,
    void* __restrict__ Cout, int M, int N, int K) {
    __shared__ __align__(16) ushort_t As[128 * 32];
    __shared__ __align__(16) ushort_t Bs[128 * 32];
    const int tid = threadIdx.x;
    const int lane = tid & 63;
    const int w = tid >> 6;
    const int wr = (w >> 1) * 64, wc = (w & 1) * 64;
    const int fr = lane & 15, fk = (lane >> 4) * 8;
    const int brow = blockIdx.x * 128, bcol = blockIdx.y * 128;

    f32x4 acc[4][4];
#pragma unroll
    for (int i = 0; i < 4; i++)
#pragma unroll
        for (int j = 0; j < 4; j++) acc[i][j] = (f32x4){0.f, 0.f, 0.f, 0.f};

    for (int k0 = 0; k0 < K; k0 += 32) {
#pragma unroll
        for (int hh = 0; hh < 2; hh++) {
            int c = hh * 256 + tid;
            int row = c >> 2, colb = (c & 3) * 8;
            async16(&A[(long)(brow + row) * K + k0 + colb], &As[c * 8]);
            async16(&Bm[(long)(bcol + row) * K + k0 + colb], &Bs[c * 8]);
        }
        __syncthreads();
        bf16x8 af[4], bfr[4];
#pragma unroll
        for (int i = 0; i < 4; i++) {
            af[i]  = *(const bf16x8*)&As[(wr + i * 16 + fr) * 32 + fk];
            bfr[i] = *(const bf16x8*)&Bs[(wc + i * 16 + fr) * 32 + fk];
        }
#pragma unroll
        for (int i = 0; i < 4; i++)
#pragma unroll
            for (int j = 0; j < 4; j++)
                acc[i][j] = __builtin_amdgcn_mfma_f32_16x16x32_bf16(af[i], bfr[j], acc[i][j], 0, 0, 0);
        __syncthreads();
    }

#pragma unroll
    for (int i = 0; i < 4; i++)
#pragma unroll
        for (int j = 0; j < 4; j++)
#pragma unroll
            for (int r = 0; r < 4; r++) {
                int row = brow + wr + i * 16 + ((lane >> 4) << 2) + r;
                int col = bcol + wc + j * 16 + fr;
                float v = acc[i][j][r];
                if constexpr (EPI == 0) {
                    int b = row >> 11, s = row & (S_LEN - 1);
                    int h = col >> 7, hd = col & 127;
                    ((ushort_t*)Cout)[(((long)(b * NH + h) * S_LEN) + s) * HDIM + hd] = f2bf(v);
                } else if constexpr (EPI == 1) {
                    int b = row >> 11, s = row & (S_LEN - 1);
                    int h = col >> 7, hd = col & 127;
                    ((ushort_t*)Cout)[(((long)(b * NH + h) * HDIM) + hd) * S_LEN + s] = f2bf(v);
                } else {
                    ((float*)Cout)[(long)row * N + col] = v;
                }
            }
}

// ---------------- Flash attention v2: 4 waves x 32 q-rows, LDS-staged K/V^T ----------
// Q,K: [BH][S][HD] bf16 (post-RoPE), Vt: [BH][HD][S] bf16, ctx out: [B][S][D] bf16
// K tile [64][128], V^T tile [128][64], both XOR-swizzled (chunk ^= row&7),
// double-buffered, 2-phase pipeline (stage t+1 before compute t).
__global__ __launch_bounds__(256) void attn_fwd_v2(
    const ushort_t* __restrict__ Q, const ushort_t* __restrict__ K,
    const ushort_t* __restrict__ Vt, ushort_t* __restrict__ ctx) {
    __shared__ __align__(16) ushort_t Ks[2][64 * 128];
    __shared__ __align__(16) ushort_t Vs[2][128 * 64];
    __shared__ __align__(16) ushort_t Pls[4][32 * 64];

    const int tid = threadIdx.x;
    const int lane = tid & 63;
    const int w = tid >> 6;
    const int g = lane >> 4;
    const int fr = lane & 15;
    const int fk = g * 8;
    // pair big and small q-blocks for load balance: 0,15,1,14,...
    const int qxr = blockIdx.x;
    const int qb = (qxr & 1) ? (15 - (qxr >> 1)) : (qxr >> 1);
    const int q0 = qb * 128;
    const int bh = blockIdx.y;
    const int b = bh >> 4, h = bh & 15;

    const ushort_t* Qb = Q + (long)bh * S_LEN * HDIM;
    const ushort_t* Kb = K + (long)bh * S_LEN * HDIM;
    const ushort_t* Vb = Vt + (long)bh * HDIM * S_LEN;

    // per-thread staging source offsets (constant across tiles)
    int koff[4], voff[4], kdst[4], vdst[4];
#pragma unroll
    for (int r = 0; r < 4; r++) {
        int ci = r * 256 + tid;
        int krow = ci >> 4, kwc = ci & 15;
        koff[r] = krow * HDIM + ((kwc ^ (krow & 7)) * 8);
        kdst[r] = ci * 8;
        int vrow = ci >> 3, vwc = ci & 7;
        voff[r] = vrow * S_LEN + ((vwc ^ (vrow & 7)) * 8);
        vdst[r] = ci * 8;
    }

    bf16x8 qf[2][4];
#pragma unroll
    for (int m = 0; m < 2; m++)
#pragma unroll
        for (int t = 0; t < 4; t++)
            qf[m][t] = *(const bf16x8*)&Qb[(long)(q0 + w * 32 + m * 16 + fr) * HDIM + t * 32 + fk];

    f32x4 o[2][8];
#pragma unroll
    for (int m = 0; m < 2; m++)
#pragma unroll
        for (int i = 0; i < 8; i++) o[m][i] = (f32x4){0.f, 0.f, 0.f, 0.f};
    float mrun[2][4], lrun[2][4];
#pragma unroll
    for (int m = 0; m < 2; m++)
#pragma unroll
        for (int r = 0; r < 4; r++) { mrun[m][r] = -1e30f; lrun[m][r] = 0.f; }

    const float scale = 0.08838834764831845f; // 1/sqrt(128)
    const int nt = qb * 2 + 2;
    const int wrow0 = q0 + w * 32;

    // prologue: stage tile 0 into buffer 0
#pragma unroll
    for (int r = 0; r < 4; r++) async16(Kb + koff[r], &Ks[0][kdst[r]]);
#pragma unroll
    for (int r = 0; r < 4; r++) async16(Vb + voff[r], &Vs[0][vdst[r]]);
    __syncthreads();

    int cur = 0;
    for (int t = 0; t < nt; ++t) {
        const int kv0 = t * 64;
        if (t + 1 < nt) {
            const ushort_t* Kg = Kb + (long)(t + 1) * 64 * HDIM;
            const ushort_t* Vg = Vb + (t + 1) * 64;
#pragma unroll
            for (int r = 0; r < 4; r++) async16(Kg + koff[r], &Ks[cur ^ 1][kdst[r]]);
#pragma unroll
            for (int r = 0; r < 4; r++) async16(Vg + voff[r], &Vs[cur ^ 1][vdst[r]]);
        }
        if (kv0 <= wrow0 + 31) { // not fully masked for this wave
            // ---- QK^T ----
            f32x4 sf[2][4];
#pragma unroll
            for (int m = 0; m < 2; m++)
#pragma unroll
                for (int c = 0; c < 4; c++) sf[m][c] = (f32x4){0.f, 0.f, 0.f, 0.f};
#pragma unroll
            for (int c = 0; c < 4; c++) {
                const int krow = c * 16 + fr;
#pragma unroll
                for (int tt = 0; tt < 4; tt++) {
                    bf16x8 kb = *(const bf16x8*)&Ks[cur][krow * 128 + (((tt * 4 + g) ^ (krow & 7)) * 8)];
#pragma unroll
                    for (int m = 0; m < 2; m++)
                        sf[m][c] = __builtin_amdgcn_mfma_f32_16x16x32_bf16(qf[m][tt], kb, sf[m][c], 0, 0, 0);
                }
            }
            // ---- scale + causal mask ----
            const bool maskedW = (kv0 + 63 > wrow0);
            if (!maskedW) {
#pragma unroll
                for (int m = 0; m < 2; m++)
#pragma unroll
                    for (int c = 0; c < 4; c++)
#pragma unroll
                        for (int r = 0; r < 4; r++) sf[m][c][r] *= scale;
            } else {
#pragma unroll
                for (int m = 0; m < 2; m++)
#pragma unroll
                    for (int c = 0; c < 4; c++) {
                        int col = kv0 + c * 16 + fr;
#pragma unroll
                        for (int r = 0; r < 4; r++) {
                            int row = wrow0 + m * 16 + g * 4 + r;
                            sf[m][c][r] = (col <= row) ? sf[m][c][r] * scale : -1e30f;
                        }
                    }
            }
            // ---- online softmax (per reg-row, 16-lane group reduce) ----
#pragma unroll
            for (int m = 0; m < 2; m++)
#pragma unroll
                for (int r = 0; r < 4; r++) {
                    float vmax = fmaxf(fmaxf(sf[m][0][r], sf[m][1][r]), fmaxf(sf[m][2][r], sf[m][3][r]));
                    vmax = fmaxf(vmax, __shfl_xor(vmax, 8));
                    vmax = fmaxf(vmax, __shfl_xor(vmax, 4));
                    vmax = fmaxf(vmax, __shfl_xor(vmax, 2));
                    vmax = fmaxf(vmax, __shfl_xor(vmax, 1));
                    float nm = fmaxf(mrun[m][r], vmax);
                    float alpha = __expf(mrun[m][r] - nm);
                    mrun[m][r] = nm;
                    float rs = 0.f;
#pragma unroll
                    for (int c = 0; c < 4; c++) {
                        float p = __expf(sf[m][c][r] - nm);
                        sf[m][c][r] = p;
                        rs += p;
                    }
                    rs += __shfl_xor(rs, 8);
                    rs += __shfl_xor(rs, 4);
                    rs += __shfl_xor(rs, 2);
                    rs += __shfl_xor(rs, 1);
                    lrun[m][r] = lrun[m][r] * alpha + rs;
#pragma unroll
                    for (int dt = 0; dt < 8; dt++) o[m][dt][r] *= alpha;
                }
            // ---- P -> LDS (swizzled), C-layout -> A-layout ----
#pragma unroll
            for (int m = 0; m < 2; m++)
#pragma unroll
                for (int c = 0; c < 4; c++)
#pragma unroll
                    for (int r = 0; r < 4; r++) {
                        int row_p = m * 16 + g * 4 + r;
                        Pls[w][row_p * 64 + (((c * 2 + (fr >> 3)) ^ (row_p & 7)) * 8) + (fr & 7)] =
                            f2bf(sf[m][c][r]);
                    }
            bf16x8 pa[2][2];
#pragma unroll
            for (int m = 0; m < 2; m++)
#pragma unroll
                for (int hh = 0; hh < 2; hh++)
                    pa[m][hh] = *(const bf16x8*)&Pls[w][(m * 16 + fr) * 64 + (((hh * 4 + g) ^ (fr & 7)) * 8)];
            // ---- PV ----
#pragma unroll
            for (int dt = 0; dt < 8; dt++) {
                const int vrow = dt * 16 + fr;
#pragma unroll
                for (int hh = 0; hh < 2; hh++) {
                    bf16x8 vb = *(const bf16x8*)&Vs[cur][vrow * 64 + (((hh * 4 + g) ^ (vrow & 7)) * 8)];
#pragma unroll
                    for (int m = 0; m < 2; m++)
                        o[m][dt] = __builtin_amdgcn_mfma_f32_16x16x32_bf16(pa[m][hh], vb, o[m][dt], 0, 0, 0);
                }
            }
        }
        __syncthreads();
        cur ^= 1;
    }

    long obase = ((long)b * S_LEN) * DMODEL + (long)h * HDIM;
#pragma unroll
    for (int m = 0; m < 2; m++)
#pragma unroll
        for (int dt = 0; dt < 8; dt++)
#pragma unroll
            for (int r = 0; r < 4; r++) {
                int srow = wrow0 + m * 16 + g * 4 + r;
                ctx[obase + (long)srow * DMODEL + dt * 16 + fr] = f2bf(o[m][dt][r] / lrun[m][r]);
            }
}

extern "C" void kernel_launch(void* const* d_in, const int* in_sizes, int n_in,
                              void* d_out, int out_size, void* d_ws, size_t ws_size,
                              hipStream_t stream) {
    const float* hs = (const float*)d_in[0];
    const float* Wq = (const float*)d_in[1];
    const float* Wk = (const float*)d_in[2];
    const float* Wv = (const float*)d_in[3];
    const float* Wo = (const float*)d_in[4];
    float* out = (float*)d_out;

    size_t off = 0;
    char* wsb = (char*)d_ws;
    auto carve = [&](size_t bytes) { void* p = wsb + off; off += bytes; return p; };

    ushort_t* Xb   = (ushort_t*)carve((size_t)M_ROWS * DMODEL * 2);
    ushort_t* Wqb  = (ushort_t*)carve((size_t)DMODEL * DMODEL * 2);
    ushort_t* Wkb  = (ushort_t*)carve((size_t)DMODEL * DMODEL * 2);
    ushort_t* Wvb  = (ushort_t*)carve((size_t)DMODEL * DMODEL * 2);
    ushort_t* Wob  = (ushort_t*)carve((size_t)DMODEL * DMODEL * 2);
    ushort_t* Qb   = (ushort_t*)carve((size_t)BATCH * NH * S_LEN * HDIM * 2);
    ushort_t* Kb   = (ushort_t*)carve((size_t)BATCH * NH * S_LEN * HDIM * 2);
    ushort_t* Vtb  = (ushort_t*)carve((size_t)BATCH * NH * S_LEN * HDIM * 2);
    ushort_t* ctxb = (ushort_t*)carve((size_t)M_ROWS * DMODEL * 2);
    float* cosT    = (float*)carve((size_t)S_LEN * 64 * 4);
    float* sinT    = (float*)carve((size_t)S_LEN * 64 * 4);

    const int nX = M_ROWS * DMODEL;   // 8388608
    const int nW = DMODEL * DMODEL;   // 4194304

    cvt_bf16<<<(nX / 4) / 256, 256, 0, stream>>>(hs, Xb, nX / 4);
    cvt_bf16<<<(nW / 4) / 256, 256, 0, stream>>>(Wq, Wqb, nW / 4);
    cvt_bf16<<<(nW / 4) / 256, 256, 0, stream>>>(Wk, Wkb, nW / 4);
    cvt_bf16<<<(nW / 4) / 256, 256, 0, stream>>>(Wv, Wvb, nW / 4);
    cvt_bf16<<<(nW / 4) / 256, 256, 0, stream>>>(Wo, Wob, nW / 4);
    rope_tables<<<(S_LEN * 64) / 256, 256, 0, stream>>>(cosT, sinT);

    dim3 gg(M_ROWS / 128, DMODEL / 128);
    gemm_bt<0><<<gg, 256, 0, stream>>>(Xb, Wqb, Qb, M_ROWS, DMODEL, DMODEL);
    gemm_bt<0><<<gg, 256, 0, stream>>>(Xb, Wkb, Kb, M_ROWS, DMODEL, DMODEL);
    gemm_bt<1><<<gg, 256, 0, stream>>>(Xb, Wvb, Vtb, M_ROWS, DMODEL, DMODEL);

    rope_inplace<<<(BATCH * NH * S_LEN * 64) / 256, 256, 0, stream>>>(Qb, Kb, cosT, sinT);

    attn_fwd_v2<<<dim3(S_LEN / 128, BATCH * NH), 256, 0, stream>>>(Qb, Kb, Vtb, ctxb);

    gemm_bt<2><<<gg, 256, 0, stream>>>(ctxb, Wob, out, M_ROWS, DMODEL, DMODEL);
}

// Round 3
// 425.452 us; speedup vs baseline: 1.4986x; 1.1639x over previous
//
#include <hip/hip_runtime.h>

typedef unsigned short ushort_t;
typedef __bf16 bf16x8 __attribute__((ext_vector_type(8)));
typedef float f32x4 __attribute__((ext_vector_type(4)));

#define S_LEN 2048
#define DMODEL 2048
#define NH 16
#define HDIM 128
#define BATCH 2
#define M_ROWS (BATCH * S_LEN) // 4096

__device__ __forceinline__ ushort_t f2bf(float f) {
    union { float f; unsigned u; } v; v.f = f;
    unsigned r = (v.u + 0x7fffu + ((v.u >> 16) & 1u)) >> 16;
    return (ushort_t)r;
}
__device__ __forceinline__ float bf2f(ushort_t u) {
    union { unsigned u; float f; } v; v.u = ((unsigned)u) << 16;
    return v.f;
}
__device__ __forceinline__ void st_bf(ushort_t* p, float f) {
    *(__bf16*)p = (__bf16)f;
}

__device__ __forceinline__ void async16(const void* g, void* l) {
    __builtin_amdgcn_global_load_lds(
        (const __attribute__((address_space(1))) void*)g,
        (__attribute__((address_space(3))) void*)l, 16, 0, 0);
}

// ---------------- fp32 -> bf16 (4 elems/thread) ----------------
__global__ void cvt_bf16(const float* __restrict__ in, ushort_t* __restrict__ out, int n4) {
    int i = blockIdx.x * blockDim.x + threadIdx.x;
    if (i >= n4) return;
    float4 f = ((const float4*)in)[i];
    ushort4 u;
    u.x = f2bf(f.x); u.y = f2bf(f.y); u.z = f2bf(f.z); u.w = f2bf(f.w);
    ((ushort4*)out)[i] = u;
}

// ---------------- RoPE tables [S][64] ----------------
__global__ void rope_tables(float* __restrict__ cosT, float* __restrict__ sinT) {
    int i = blockIdx.x * blockDim.x + threadIdx.x; // 2048*64
    int s = i >> 6, f = i & 63;
    float inv = powf(10000.0f, -(float)(2 * f) / 128.0f);
    float ang = (float)s * inv;
    cosT[i] = cosf(ang);
    sinT[i] = sinf(ang);
}

// ---------------- RoPE in-place on Q and K ([BH][S][HD] bf16) ----------------
__global__ void rope_inplace(ushort_t* __restrict__ Q, ushort_t* __restrict__ K,
                             const float* __restrict__ cosT, const float* __restrict__ sinT) {
    long i = (long)blockIdx.x * blockDim.x + threadIdx.x; // 32*2048*64
    int f = (int)(i & 63);
    long t = i >> 6;
    int s = (int)(t & (S_LEN - 1));
    int bh = (int)(t >> 11);
    long base = ((long)bh * S_LEN + s) * HDIM;
    float c = cosT[s * 64 + f], sn = sinT[s * 64 + f];
    float a0 = bf2f(Q[base + f]), a1 = bf2f(Q[base + 64 + f]);
    Q[base + f]      = f2bf(a0 * c - a1 * sn);
    Q[base + 64 + f] = f2bf(a1 * c + a0 * sn);
    float b0 = bf2f(K[base + f]), b1 = bf2f(K[base + 64 + f]);
    K[base + f]      = f2bf(b0 * c - b1 * sn);
    K[base + 64 + f] = f2bf(b1 * c + b0 * sn);
}

// ---------------- GEMM: C[i][j] = sum_k A[i][k] * B[j][k]  (both row-major [.,K]) ----
// 128x128 tile, BK=32, 256 threads (4 waves, 2x2 of 64x64), m97-style structure.
// EPI: 0 = scatter bf16 to [B,H,S,HD]; 1 = scatter bf16 to [B,H,HD,S]; 2 = fp32 row-major.
template <int EPI>
__global__ __launch_bounds__(256) void gemm_bt(
    const ushort_t* __restrict__ A, const ushort_t* __restrict__ Bm,
    void* __restrict__ Cout, int M, int N, int K) {
    __shared__ __align__(16) ushort_t As[128 * 32];
    __shared__ __align__(16) ushort_t Bs[128 * 32];
    const int tid = threadIdx.x;
    const int lane = tid & 63;
    const int w = tid >> 6;
    const int wr = (w >> 1) * 64, wc = (w & 1) * 64;
    const int fr = lane & 15, fk = (lane >> 4) * 8;
    const int brow = blockIdx.x * 128, bcol = blockIdx.y * 128;

    f32x4 acc[4][4];
#pragma unroll
    for (int i = 0; i < 4; i++)
#pragma unroll
        for (int j = 0; j < 4; j++) acc[i][j] = (f32x4){0.f, 0.f, 0.f, 0.f};

    for (int k0 = 0; k0 < K; k0 += 32) {
#pragma unroll
        for (int hh = 0; hh < 2; hh++) {
            int c = hh * 256 + tid;
            int row = c >> 2, colb = (c & 3) * 8;
            async16(&A[(long)(brow + row) * K + k0 + colb], &As[c * 8]);
            async16(&Bm[(long)(bcol + row) * K + k0 + colb], &Bs[c * 8]);
        }
        __syncthreads();
        bf16x8 af[4], bfr[4];
#pragma unroll
        for (int i = 0; i < 4; i++) {
            af[i]  = *(const bf16x8*)&As[(wr + i * 16 + fr) * 32 + fk];
            bfr[i] = *(const bf16x8*)&Bs[(wc + i * 16 + fr) * 32 + fk];
        }
#pragma unroll
        for (int i = 0; i < 4; i++)
#pragma unroll
            for (int j = 0; j < 4; j++)
                acc[i][j] = __builtin_amdgcn_mfma_f32_16x16x32_bf16(af[i], bfr[j], acc[i][j], 0, 0, 0);
        __syncthreads();
    }

#pragma unroll
    for (int i = 0; i < 4; i++)
#pragma unroll
        for (int j = 0; j < 4; j++)
#pragma unroll
            for (int r = 0; r < 4; r++) {
                int row = brow + wr + i * 16 + ((lane >> 4) << 2) + r;
                int col = bcol + wc + j * 16 + fr;
                float v = acc[i][j][r];
                if constexpr (EPI == 0) {
                    int b = row >> 11, s = row & (S_LEN - 1);
                    int h = col >> 7, hd = col & 127;
                    ((ushort_t*)Cout)[(((long)(b * NH + h) * S_LEN) + s) * HDIM + hd] = f2bf(v);
                } else if constexpr (EPI == 1) {
                    int b = row >> 11, s = row & (S_LEN - 1);
                    int h = col >> 7, hd = col & 127;
                    ((ushort_t*)Cout)[(((long)(b * NH + h) * HDIM) + hd) * S_LEN + s] = f2bf(v);
                } else {
                    ((float*)Cout)[(long)row * N + col] = v;
                }
            }
}

// ---------------- Flash attention v3: swapped QK^T, 4 waves x 32 q-rows ----------
// Q,K: [BH][S][HD] bf16 (post-RoPE), Vt: [BH][HD][S] bf16, ctx out: [B][S][D] bf16
// QK^T computed as mfma(K,Q) so each lane owns a 16-kv slice of ONE q-row per m:
// softmax reduce = in-lane tree + 2 shuffles. PV = mfma(Vt, P) with P as B-operand.
__global__ __launch_bounds__(256) void attn_fwd_v3(
    const ushort_t* __restrict__ Q, const ushort_t* __restrict__ K,
    const ushort_t* __restrict__ Vt, ushort_t* __restrict__ ctx) {
    __shared__ __align__(16) ushort_t Ks[2][64 * 128];
    __shared__ __align__(16) ushort_t Vs[2][128 * 64];
    __shared__ __align__(16) ushort_t Pls[4][32 * 64];

    const int tid = threadIdx.x;
    const int lane = tid & 63;
    const int w = tid >> 6;
    const int g = lane >> 4;
    const int fr = lane & 15;
    const int fk = g * 8;
    // pair big and small q-blocks for load balance: 0,15,1,14,...
    const int qxr = blockIdx.x;
    const int qb = (qxr & 1) ? (15 - (qxr >> 1)) : (qxr >> 1);
    const int q0 = qb * 128;
    const int bh = blockIdx.y;
    const int b = bh >> 4, h = bh & 15;

    const ushort_t* Qb = Q + (long)bh * S_LEN * HDIM;
    const ushort_t* Kb = K + (long)bh * S_LEN * HDIM;
    const ushort_t* Vb = Vt + (long)bh * HDIM * S_LEN;

    // per-thread staging source offsets (constant across tiles)
    int koff[4], voff[4], kdst[4], vdst[4];
#pragma unroll
    for (int r = 0; r < 4; r++) {
        int ci = r * 256 + tid;
        int krow = ci >> 4, kwc = ci & 15;
        koff[r] = krow * HDIM + ((kwc ^ (krow & 7)) * 8);
        kdst[r] = ci * 8;
        int vrow = ci >> 3, vwc = ci & 7;
        voff[r] = vrow * S_LEN + ((vwc ^ (vrow & 7)) * 8);
        vdst[r] = ci * 8;
    }

    bf16x8 qf[2][4];
#pragma unroll
    for (int m = 0; m < 2; m++)
#pragma unroll
        for (int t = 0; t < 4; t++)
            qf[m][t] = *(const bf16x8*)&Qb[(long)(q0 + w * 32 + m * 16 + fr) * HDIM + t * 32 + fk];

    f32x4 o[2][8];
#pragma unroll
    for (int m = 0; m < 2; m++)
#pragma unroll
        for (int i = 0; i < 8; i++) o[m][i] = (f32x4){0.f, 0.f, 0.f, 0.f};
    float mrun[2] = {-1e30f, -1e30f};
    float lrun[2] = {0.f, 0.f};

    const float scale = 0.08838834764831845f; // 1/sqrt(128)
    const int nt = qb * 2 + 2;
    const int wrow0 = q0 + w * 32;

    // prologue: stage tile 0 into buffer 0
#pragma unroll
    for (int r = 0; r < 4; r++) async16(Kb + koff[r], &Ks[0][kdst[r]]);
#pragma unroll
    for (int r = 0; r < 4; r++) async16(Vb + voff[r], &Vs[0][vdst[r]]);
    __syncthreads();

    int cur = 0;
    for (int t = 0; t < nt; ++t) {
        const int kv0 = t * 64;
        if (t + 1 < nt) {
            const ushort_t* Kg = Kb + (long)(t + 1) * 64 * HDIM;
            const ushort_t* Vg = Vb + (t + 1) * 64;
#pragma unroll
            for (int r = 0; r < 4; r++) async16(Kg + koff[r], &Ks[cur ^ 1][kdst[r]]);
#pragma unroll
            for (int r = 0; r < 4; r++) async16(Vg + voff[r], &Vs[cur ^ 1][vdst[r]]);
        }
        if (kv0 <= wrow0 + 31) { // not fully masked for this wave
            // ---- QK^T (swapped: A=K rows=kv, B=Q cols=q) ----
            f32x4 sf[2][4]; // [m][c]: rows kv = kv0+c*16+g*4+r, col q = wrow0+m*16+fr
#pragma unroll
            for (int m = 0; m < 2; m++)
#pragma unroll
                for (int c = 0; c < 4; c++) sf[m][c] = (f32x4){0.f, 0.f, 0.f, 0.f};
            __builtin_amdgcn_s_setprio(1);
#pragma unroll
            for (int c = 0; c < 4; c++) {
                const int krow = c * 16 + fr;
#pragma unroll
                for (int tt = 0; tt < 4; tt++) {
                    bf16x8 kb = *(const bf16x8*)&Ks[cur][krow * 128 + (((tt * 4 + g) ^ (krow & 7)) * 8)];
#pragma unroll
                    for (int m = 0; m < 2; m++)
                        sf[m][c] = __builtin_amdgcn_mfma_f32_16x16x32_bf16(kb, qf[m][tt], sf[m][c], 0, 0, 0);
                }
            }
            __builtin_amdgcn_s_setprio(0);
            // ---- scale + causal mask ----
            const bool maskedW = (kv0 + 63 > wrow0);
            if (!maskedW) {
#pragma unroll
                for (int m = 0; m < 2; m++)
#pragma unroll
                    for (int c = 0; c < 4; c++)
#pragma unroll
                        for (int r = 0; r < 4; r++) sf[m][c][r] *= scale;
            } else {
#pragma unroll
                for (int m = 0; m < 2; m++) {
                    const int q = wrow0 + m * 16 + fr;
#pragma unroll
                    for (int c = 0; c < 4; c++) {
#pragma unroll
                        for (int r = 0; r < 4; r++) {
                            int kv = kv0 + c * 16 + g * 4 + r;
                            sf[m][c][r] = (kv <= q) ? sf[m][c][r] * scale : -1e30f;
                        }
                    }
                }
            }
            // ---- online softmax: lane owns 16 kv of row q=wrow0+m*16+fr ----
#pragma unroll
            for (int m = 0; m < 2; m++) {
                float vmax = -1e30f;
#pragma unroll
                for (int c = 0; c < 4; c++) {
                    float t0 = fmaxf(fmaxf(sf[m][c][0], sf[m][c][1]), fmaxf(sf[m][c][2], sf[m][c][3]));
                    vmax = fmaxf(vmax, t0);
                }
                vmax = fmaxf(vmax, __shfl_xor(vmax, 16));
                vmax = fmaxf(vmax, __shfl_xor(vmax, 32));
                // defer-max (T13): only rescale when max grew by > 8
                if (!__all(vmax - mrun[m] <= 8.f)) {
                    float nm = fmaxf(mrun[m], vmax);
                    float alpha = __expf(mrun[m] - nm);
                    mrun[m] = nm;
                    lrun[m] *= alpha;
#pragma unroll
                    for (int dt = 0; dt < 8; dt++) o[m][dt] *= alpha;
                }
                float rs = 0.f;
#pragma unroll
                for (int c = 0; c < 4; c++)
#pragma unroll
                    for (int r = 0; r < 4; r++) {
                        float p = __expf(sf[m][c][r] - mrun[m]);
                        sf[m][c][r] = p;
                        rs += p;
                    }
                rs += __shfl_xor(rs, 16);
                rs += __shfl_xor(rs, 32);
                lrun[m] += rs;
            }
            // ---- P -> LDS as [q=32][kv=64], XOR-swizzled ----
#pragma unroll
            for (int m = 0; m < 2; m++)
#pragma unroll
                for (int c = 0; c < 4; c++)
#pragma unroll
                    for (int r = 0; r < 4; r++) {
                        int kvloc = c * 16 + g * 4 + r;
                        st_bf(&Pls[w][(m * 16 + fr) * 64 + (kvloc ^ ((fr & 7) << 3))], sf[m][c][r]);
                    }
            bf16x8 pa[2][2]; // B-frag: P[kv = hh*32+g*8+j][q = m*16+fr]
#pragma unroll
            for (int m = 0; m < 2; m++)
#pragma unroll
                for (int hh = 0; hh < 2; hh++)
                    pa[m][hh] = *(const bf16x8*)&Pls[w][(m * 16 + fr) * 64 + ((hh * 32 + g * 8) ^ ((fr & 7) << 3))];
            // ---- PV: O^T-tiles = mfma(A=V^T rows=d, B=P cols=q) ----
            __builtin_amdgcn_s_setprio(1);
#pragma unroll
            for (int dt = 0; dt < 8; dt++) {
                const int vrow = dt * 16 + fr;
#pragma unroll
                for (int hh = 0; hh < 2; hh++) {
                    bf16x8 vb = *(const bf16x8*)&Vs[cur][vrow * 64 + (((hh * 4 + g) ^ (vrow & 7)) * 8)];
#pragma unroll
                    for (int m = 0; m < 2; m++)
                        o[m][dt] = __builtin_amdgcn_mfma_f32_16x16x32_bf16(vb, pa[m][hh], o[m][dt], 0, 0, 0);
                }
            }
            __builtin_amdgcn_s_setprio(0);
        }
        __syncthreads();
        cur ^= 1;
    }

    // o[m][dt][r]: q = wrow0+m*16+fr, d = dt*16+g*4+r
    long obase = ((long)b * S_LEN) * DMODEL + (long)h * HDIM;
#pragma unroll
    for (int m = 0; m < 2; m++) {
        const float inv = 1.0f / lrun[m];
        const int q = wrow0 + m * 16 + fr;
#pragma unroll
        for (int dt = 0; dt < 8; dt++)
#pragma unroll
            for (int r = 0; r < 4; r++) {
                int d = dt * 16 + g * 4 + r;
                ctx[obase + (long)q * DMODEL + d] = f2bf(o[m][dt][r] * inv);
            }
    }
}

extern "C" void kernel_launch(void* const* d_in, const int* in_sizes, int n_in,
                              void* d_out, int out_size, void* d_ws, size_t ws_size,
                              hipStream_t stream) {
    const float* hs = (const float*)d_in[0];
    const float* Wq = (const float*)d_in[1];
    const float* Wk = (const float*)d_in[2];
    const float* Wv = (const float*)d_in[3];
    const float* Wo = (const float*)d_in[4];
    float* out = (float*)d_out;

    size_t off = 0;
    char* wsb = (char*)d_ws;
    auto carve = [&](size_t bytes) { void* p = wsb + off; off += bytes; return p; };

    ushort_t* Xb   = (ushort_t*)carve((size_t)M_ROWS * DMODEL * 2);
    ushort_t* Wqb  = (ushort_t*)carve((size_t)DMODEL * DMODEL * 2);
    ushort_t* Wkb  = (ushort_t*)carve((size_t)DMODEL * DMODEL * 2);
    ushort_t* Wvb  = (ushort_t*)carve((size_t)DMODEL * DMODEL * 2);
    ushort_t* Wob  = (ushort_t*)carve((size_t)DMODEL * DMODEL * 2);
    ushort_t* Qb   = (ushort_t*)carve((size_t)BATCH * NH * S_LEN * HDIM * 2);
    ushort_t* Kb   = (ushort_t*)carve((size_t)BATCH * NH * S_LEN * HDIM * 2);
    ushort_t* Vtb  = (ushort_t*)carve((size_t)BATCH * NH * S_LEN * HDIM * 2);
    ushort_t* ctxb = (ushort_t*)carve((size_t)M_ROWS * DMODEL * 2);
    float* cosT    = (float*)carve((size_t)S_LEN * 64 * 4);
    float* sinT    = (float*)carve((size_t)S_LEN * 64 * 4);

    const int nX = M_ROWS * DMODEL;   // 8388608
    const int nW = DMODEL * DMODEL;   // 4194304

    cvt_bf16<<<(nX / 4) / 256, 256, 0, stream>>>(hs, Xb, nX / 4);
    cvt_bf16<<<(nW / 4) / 256, 256, 0, stream>>>(Wq, Wqb, nW / 4);
    cvt_bf16<<<(nW / 4) / 256, 256, 0, stream>>>(Wk, Wkb, nW / 4);
    cvt_bf16<<<(nW / 4) / 256, 256, 0, stream>>>(Wv, Wvb, nW / 4);
    cvt_bf16<<<(nW / 4) / 256, 256, 0, stream>>>(Wo, Wob, nW / 4);
    rope_tables<<<(S_LEN * 64) / 256, 256, 0, stream>>>(cosT, sinT);

    dim3 gg(M_ROWS / 128, DMODEL / 128);
    gemm_bt<0><<<gg, 256, 0, stream>>>(Xb, Wqb, Qb, M_ROWS, DMODEL, DMODEL);
    gemm_bt<0><<<gg, 256, 0, stream>>>(Xb, Wkb, Kb, M_ROWS, DMODEL, DMODEL);
    gemm_bt<1><<<gg, 256, 0, stream>>>(Xb, Wvb, Vtb, M_ROWS, DMODEL, DMODEL);

    rope_inplace<<<(BATCH * NH * S_LEN * 64) / 256, 256, 0, stream>>>(Qb, Kb, cosT, sinT);

    attn_fwd_v3<<<dim3(S_LEN / 128, BATCH * NH), 256, 0, stream>>>(Qb, Kb, Vtb, ctxb);

    gemm_bt<2><<<gg, 256, 0, stream>>>(ctxb, Wob, out, M_ROWS, DMODEL, DMODEL);
}

// Round 4
// 395.775 us; speedup vs baseline: 1.6110x; 1.0750x over previous
//
#include <hip/hip_runtime.h>

typedef unsigned short ushort_t;
typedef __bf16 bf16x8 __attribute__((ext_vector_type(8)));
typedef float f32x4 __attribute__((ext_vector_type(4)));

#define S_LEN 2048
#define DMODEL 2048
#define NH 16
#define HDIM 128
#define BATCH 2
#define M_ROWS (BATCH * S_LEN) // 4096

__device__ __forceinline__ ushort_t f2bf(float f) {
    union { float f; unsigned u; } v; v.f = f;
    unsigned r = (v.u + 0x7fffu + ((v.u >> 16) & 1u)) >> 16;
    return (ushort_t)r;
}
__device__ __forceinline__ float bf2f(ushort_t u) {
    union { unsigned u; float f; } v; v.u = ((unsigned)u) << 16;
    return v.f;
}
__device__ __forceinline__ void st_bf(ushort_t* p, float f) {
    *(__bf16*)p = (__bf16)f;
}

__device__ __forceinline__ void async16(const void* g, void* l) {
    __builtin_amdgcn_global_load_lds(
        (const __attribute__((address_space(1))) void*)g,
        (__attribute__((address_space(3))) void*)l, 16, 0, 0);
}

// ---------------- fp32 -> bf16 (4 elems/thread) ----------------
__global__ void cvt_bf16(const float* __restrict__ in, ushort_t* __restrict__ out, int n4) {
    int i = blockIdx.x * blockDim.x + threadIdx.x;
    if (i >= n4) return;
    float4 f = ((const float4*)in)[i];
    ushort4 u;
    u.x = f2bf(f.x); u.y = f2bf(f.y); u.z = f2bf(f.z); u.w = f2bf(f.w);
    ((ushort4*)out)[i] = u;
}

// ---------------- RoPE tables [S][64] ----------------
__global__ void rope_tables(float* __restrict__ cosT, float* __restrict__ sinT) {
    int i = blockIdx.x * blockDim.x + threadIdx.x; // 2048*64
    int s = i >> 6, f = i & 63;
    float inv = powf(10000.0f, -(float)(2 * f) / 128.0f);
    float ang = (float)s * inv;
    cosT[i] = cosf(ang);
    sinT[i] = sinf(ang);
}

// ---------------- RoPE in-place on Q and K ([BH][S][HD] bf16) ----------------
__global__ void rope_inplace(ushort_t* __restrict__ Q, ushort_t* __restrict__ K,
                             const float* __restrict__ cosT, const float* __restrict__ sinT) {
    long i = (long)blockIdx.x * blockDim.x + threadIdx.x; // 32*2048*64
    int f = (int)(i & 63);
    long t = i >> 6;
    int s = (int)(t & (S_LEN - 1));
    int bh = (int)(t >> 11);
    long base = ((long)bh * S_LEN + s) * HDIM;
    float c = cosT[s * 64 + f], sn = sinT[s * 64 + f];
    float a0 = bf2f(Q[base + f]), a1 = bf2f(Q[base + 64 + f]);
    Q[base + f]      = f2bf(a0 * c - a1 * sn);
    Q[base + 64 + f] = f2bf(a1 * c + a0 * sn);
    float b0 = bf2f(K[base + f]), b1 = bf2f(K[base + 64 + f]);
    K[base + f]      = f2bf(b0 * c - b1 * sn);
    K[base + 64 + f] = f2bf(b1 * c + b0 * sn);
}

// ================= 8-wave GEMM: BM=128, BN=256, BK=64, 512 threads =================
// C[i][j] = sum_k A[i][k] * B[j][k], A [M][K], B [N][K] row-major bf16.
// st_16x32 swizzle: LDS elem (row,k) lives at byte (row*128 + k*2) ^ ((bit9)<<5),
// i.e. k ^= ((row>>2)&1)<<4. global_load_lds writes linearly -> pre-swizzle the
// global source address (involution), swizzle the ds_read address.
// Schedule per K-tile: prefetch next tile at top (6 global_load_lds), then 4
// quadrant sub-phases (8 MFMA each, setprio-wrapped), one barrier per tile.
// EPI 0: cols are [Q|K|V] fused (N=6144): Q/K scatter to [B,H,S,HD], V to [B,H,HD,S].
// EPI 2: fp32 row-major [M][2048].
template <int EPI>
__global__ __launch_bounds__(512) void gemm8(
    const ushort_t* __restrict__ A, const ushort_t* __restrict__ Bm,
    void* __restrict__ C0, void* __restrict__ C1, void* __restrict__ C2,
    int NB, int K) {
    __shared__ __align__(16) ushort_t As[2][128 * 64];
    __shared__ __align__(16) ushort_t Bs[2][256 * 64];
    const int tid = threadIdx.x;
    const int lane = tid & 63;
    const int w = tid >> 6;
    const int wm = w >> 2, wn = w & 3;     // 2 x 4 waves
    const int fr = lane & 15, g = lane >> 4;
    const int nwg = gridDim.x;
    const int work = (blockIdx.x & 7) * (nwg >> 3) + (blockIdx.x >> 3); // XCD grouping
    const int brow = (work / NB) * 128;
    const int bcol = (work % NB) * 256;

    // staging: pre-swizzled source coords (A: 2 rounds of 8KB, B: 4 rounds)
    int aRow[2], aK[2], bRow[4], bK[4];
#pragma unroll
    for (int q = 0; q < 2; q++) {
        int d = (q * 512 + tid) * 16;
        int s = d ^ (((d >> 9) & 1) << 5);
        aRow[q] = s >> 7; aK[q] = (s & 127) >> 1;
    }
#pragma unroll
    for (int q = 0; q < 4; q++) {
        int d = (q * 512 + tid) * 16;
        int s = d ^ (((d >> 9) & 1) << 5);
        bRow[q] = s >> 7; bK[q] = (s & 127) >> 1;
    }

    f32x4 acc[4][4];
#pragma unroll
    for (int m = 0; m < 4; m++)
#pragma unroll
        for (int n = 0; n < 4; n++) acc[m][n] = (f32x4){0.f, 0.f, 0.f, 0.f};

    auto stage = [&](int buf, int k0) {
#pragma unroll
        for (int q = 0; q < 2; q++)
            async16(&A[(long)(brow + aRow[q]) * K + k0 + aK[q]], &As[buf][(q * 512 + tid) * 8]);
#pragma unroll
        for (int q = 0; q < 4; q++)
            async16(&Bm[(long)(bcol + bRow[q]) * K + k0 + bK[q]], &Bs[buf][(q * 512 + tid) * 8]);
    };
    auto rdA = [&](int buf, int m, int ks) -> bf16x8 {
        int row = wm * 64 + m * 16 + fr;
        int off = row * 64 + ((ks * 32 + g * 8) ^ (((row >> 2) & 1) << 4));
        return *(const bf16x8*)&As[buf][off];
    };
    auto rdB = [&](int buf, int n, int ks) -> bf16x8 {
        int row = wn * 64 + n * 16 + fr;
        int off = row * 64 + ((ks * 32 + g * 8) ^ (((row >> 2) & 1) << 4));
        return *(const bf16x8*)&Bs[buf][off];
    };

    stage(0, 0);
    __syncthreads();

    const int NT = K / 64;
    int cur = 0;
    for (int kt = 0; kt < NT; ++kt) {
        if (kt + 1 < NT) stage(cur ^ 1, (kt + 1) * 64);
        bf16x8 a0[2][2], a2[2][2], bn[4][2];
        // ---- S0: read A m0,m1 + B n0,n1; MFMA m01 x n01 ----
#pragma unroll
        for (int m = 0; m < 2; m++)
#pragma unroll
            for (int ks = 0; ks < 2; ks++) a0[m][ks] = rdA(cur, m, ks);
#pragma unroll
        for (int n = 0; n < 2; n++)
#pragma unroll
            for (int ks = 0; ks < 2; ks++) bn[n][ks] = rdB(cur, n, ks);
        __builtin_amdgcn_s_setprio(1);
#pragma unroll
        for (int m = 0; m < 2; m++)
#pragma unroll
            for (int n = 0; n < 2; n++)
#pragma unroll
                for (int ks = 0; ks < 2; ks++)
                    acc[m][n] = __builtin_amdgcn_mfma_f32_16x16x32_bf16(a0[m][ks], bn[n][ks], acc[m][n], 0, 0, 0);
        __builtin_amdgcn_s_setprio(0);
        // ---- S1: read B n2,n3; MFMA m01 x n23 ----
#pragma unroll
        for (int n = 2; n < 4; n++)
#pragma unroll
            for (int ks = 0; ks < 2; ks++) bn[n][ks] = rdB(cur, n, ks);
        __builtin_amdgcn_s_setprio(1);
#pragma unroll
        for (int m = 0; m < 2; m++)
#pragma unroll
            for (int n = 2; n < 4; n++)
#pragma unroll
                for (int ks = 0; ks < 2; ks++)
                    acc[m][n] = __builtin_amdgcn_mfma_f32_16x16x32_bf16(a0[m][ks], bn[n][ks], acc[m][n], 0, 0, 0);
        __builtin_amdgcn_s_setprio(0);
        // ---- S2: read A m2,m3; MFMA m23 x n23 ----
#pragma unroll
        for (int m = 0; m < 2; m++)
#pragma unroll
            for (int ks = 0; ks < 2; ks++) a2[m][ks] = rdA(cur, m + 2, ks);
        __builtin_amdgcn_s_setprio(1);
#pragma unroll
        for (int m = 0; m < 2; m++)
#pragma unroll
            for (int n = 2; n < 4; n++)
#pragma unroll
                for (int ks = 0; ks < 2; ks++)
                    acc[m + 2][n] = __builtin_amdgcn_mfma_f32_16x16x32_bf16(a2[m][ks], bn[n][ks], acc[m + 2][n], 0, 0, 0);
        __builtin_amdgcn_s_setprio(0);
        // ---- S3: MFMA m23 x n01 (regs still live) ----
        __builtin_amdgcn_s_setprio(1);
#pragma unroll
        for (int m = 0; m < 2; m++)
#pragma unroll
            for (int n = 0; n < 2; n++)
#pragma unroll
                for (int ks = 0; ks < 2; ks++)
                    acc[m + 2][n] = __builtin_amdgcn_mfma_f32_16x16x32_bf16(a2[m][ks], bn[n][ks], acc[m + 2][n], 0, 0, 0);
        __builtin_amdgcn_s_setprio(0);
        __syncthreads();
        cur ^= 1;
    }

    // ---- epilogue ----
    const int rbase = brow + wm * 64;
    if constexpr (EPI == 0) {
        const int proj = bcol >> 11; // 0=Q, 1=K, 2=V (each 256-col block is in one proj)
        const int cbase = (bcol & 2047) + wn * 64;
        if (proj < 2) {
            ushort_t* dst = (ushort_t*)(proj == 0 ? C0 : C1);
#pragma unroll
            for (int m = 0; m < 4; m++)
#pragma unroll
                for (int n = 0; n < 4; n++) {
                    int c2 = cbase + n * 16 + fr;
                    int h = c2 >> 7, hd = c2 & 127;
#pragma unroll
                    for (int r = 0; r < 4; r++) {
                        int row = rbase + m * 16 + g * 4 + r;
                        int b = row >> 11, s = row & (S_LEN - 1);
                        dst[(((long)(b * NH + h) * S_LEN) + s) * HDIM + hd] = f2bf(acc[m][n][r]);
                    }
                }
        } else {
            ushort_t* dst = (ushort_t*)C2;
#pragma unroll
            for (int m = 0; m < 4; m++) {
                int row0 = rbase + m * 16 + g * 4;
                int b = row0 >> 11, s0 = row0 & (S_LEN - 1);
#pragma unroll
                for (int n = 0; n < 4; n++) {
                    int c2 = cbase + n * 16 + fr;
                    int h = c2 >> 7, hd = c2 & 127;
                    ushort4 u;
                    u.x = f2bf(acc[m][n][0]); u.y = f2bf(acc[m][n][1]);
                    u.z = f2bf(acc[m][n][2]); u.w = f2bf(acc[m][n][3]);
                    *(ushort4*)&dst[(((long)(b * NH + h) * HDIM) + hd) * S_LEN + s0] = u;
                }
            }
        }
    } else {
        float* dst = (float*)C0;
#pragma unroll
        for (int m = 0; m < 4; m++)
#pragma unroll
            for (int n = 0; n < 4; n++) {
                int col = bcol + wn * 64 + n * 16 + fr;
#pragma unroll
                for (int r = 0; r < 4; r++) {
                    int row = rbase + m * 16 + g * 4 + r;
                    dst[(long)row * DMODEL + col] = acc[m][n][r];
                }
            }
    }
}

// ---------------- Flash attention v3: swapped QK^T, 4 waves x 32 q-rows ----------
__global__ __launch_bounds__(256) void attn_fwd_v3(
    const ushort_t* __restrict__ Q, const ushort_t* __restrict__ K,
    const ushort_t* __restrict__ Vt, ushort_t* __restrict__ ctx) {
    __shared__ __align__(16) ushort_t Ks[2][64 * 128];
    __shared__ __align__(16) ushort_t Vs[2][128 * 64];
    __shared__ __align__(16) ushort_t Pls[4][32 * 64];

    const int tid = threadIdx.x;
    const int lane = tid & 63;
    const int w = tid >> 6;
    const int g = lane >> 4;
    const int fr = lane & 15;
    const int fk = g * 8;
    const int qxr = blockIdx.x;
    const int qb = (qxr & 1) ? (15 - (qxr >> 1)) : (qxr >> 1);
    const int q0 = qb * 128;
    const int bh = blockIdx.y;
    const int b = bh >> 4, h = bh & 15;

    const ushort_t* Qb = Q + (long)bh * S_LEN * HDIM;
    const ushort_t* Kb = K + (long)bh * S_LEN * HDIM;
    const ushort_t* Vb = Vt + (long)bh * HDIM * S_LEN;

    int koff[4], voff[4], kdst[4], vdst[4];
#pragma unroll
    for (int r = 0; r < 4; r++) {
        int ci = r * 256 + tid;
        int krow = ci >> 4, kwc = ci & 15;
        koff[r] = krow * HDIM + ((kwc ^ (krow & 7)) * 8);
        kdst[r] = ci * 8;
        int vrow = ci >> 3, vwc = ci & 7;
        voff[r] = vrow * S_LEN + ((vwc ^ (vrow & 7)) * 8);
        vdst[r] = ci * 8;
    }

    bf16x8 qf[2][4];
#pragma unroll
    for (int m = 0; m < 2; m++)
#pragma unroll
        for (int t = 0; t < 4; t++)
            qf[m][t] = *(const bf16x8*)&Qb[(long)(q0 + w * 32 + m * 16 + fr) * HDIM + t * 32 + fk];

    f32x4 o[2][8];
#pragma unroll
    for (int m = 0; m < 2; m++)
#pragma unroll
        for (int i = 0; i < 8; i++) o[m][i] = (f32x4){0.f, 0.f, 0.f, 0.f};
    float mrun[2] = {-1e30f, -1e30f};
    float lrun[2] = {0.f, 0.f};

    const float scale = 0.08838834764831845f; // 1/sqrt(128)
    const int nt = qb * 2 + 2;
    const int wrow0 = q0 + w * 32;

#pragma unroll
    for (int r = 0; r < 4; r++) async16(Kb + koff[r], &Ks[0][kdst[r]]);
#pragma unroll
    for (int r = 0; r < 4; r++) async16(Vb + voff[r], &Vs[0][vdst[r]]);
    __syncthreads();

    int cur = 0;
    for (int t = 0; t < nt; ++t) {
        const int kv0 = t * 64;
        if (t + 1 < nt) {
            const ushort_t* Kg = Kb + (long)(t + 1) * 64 * HDIM;
            const ushort_t* Vg = Vb + (t + 1) * 64;
#pragma unroll
            for (int r = 0; r < 4; r++) async16(Kg + koff[r], &Ks[cur ^ 1][kdst[r]]);
#pragma unroll
            for (int r = 0; r < 4; r++) async16(Vg + voff[r], &Vs[cur ^ 1][vdst[r]]);
        }
        if (kv0 <= wrow0 + 31) {
            f32x4 sf[2][4];
#pragma unroll
            for (int m = 0; m < 2; m++)
#pragma unroll
                for (int c = 0; c < 4; c++) sf[m][c] = (f32x4){0.f, 0.f, 0.f, 0.f};
            __builtin_amdgcn_s_setprio(1);
#pragma unroll
            for (int c = 0; c < 4; c++) {
                const int krow = c * 16 + fr;
#pragma unroll
                for (int tt = 0; tt < 4; tt++) {
                    bf16x8 kb = *(const bf16x8*)&Ks[cur][krow * 128 + (((tt * 4 + g) ^ (krow & 7)) * 8)];
#pragma unroll
                    for (int m = 0; m < 2; m++)
                        sf[m][c] = __builtin_amdgcn_mfma_f32_16x16x32_bf16(kb, qf[m][tt], sf[m][c], 0, 0, 0);
                }
            }
            __builtin_amdgcn_s_setprio(0);
            const bool maskedW = (kv0 + 63 > wrow0);
            if (!maskedW) {
#pragma unroll
                for (int m = 0; m < 2; m++)
#pragma unroll
                    for (int c = 0; c < 4; c++)
#pragma unroll
                        for (int r = 0; r < 4; r++) sf[m][c][r] *= scale;
            } else {
#pragma unroll
                for (int m = 0; m < 2; m++) {
                    const int q = wrow0 + m * 16 + fr;
#pragma unroll
                    for (int c = 0; c < 4; c++) {
#pragma unroll
                        for (int r = 0; r < 4; r++) {
                            int kv = kv0 + c * 16 + g * 4 + r;
                            sf[m][c][r] = (kv <= q) ? sf[m][c][r] * scale : -1e30f;
                        }
                    }
                }
            }
#pragma unroll
            for (int m = 0; m < 2; m++) {
                float vmax = -1e30f;
#pragma unroll
                for (int c = 0; c < 4; c++) {
                    float t0 = fmaxf(fmaxf(sf[m][c][0], sf[m][c][1]), fmaxf(sf[m][c][2], sf[m][c][3]));
                    vmax = fmaxf(vmax, t0);
                }
                vmax = fmaxf(vmax, __shfl_xor(vmax, 16));
                vmax = fmaxf(vmax, __shfl_xor(vmax, 32));
                if (!__all(vmax - mrun[m] <= 8.f)) {
                    float nm = fmaxf(mrun[m], vmax);
                    float alpha = __expf(mrun[m] - nm);
                    mrun[m] = nm;
                    lrun[m] *= alpha;
#pragma unroll
                    for (int dt = 0; dt < 8; dt++) o[m][dt] *= alpha;
                }
                float rs = 0.f;
#pragma unroll
                for (int c = 0; c < 4; c++)
#pragma unroll
                    for (int r = 0; r < 4; r++) {
                        float p = __expf(sf[m][c][r] - mrun[m]);
                        sf[m][c][r] = p;
                        rs += p;
                    }
                rs += __shfl_xor(rs, 16);
                rs += __shfl_xor(rs, 32);
                lrun[m] += rs;
            }
#pragma unroll
            for (int m = 0; m < 2; m++)
#pragma unroll
                for (int c = 0; c < 4; c++)
#pragma unroll
                    for (int r = 0; r < 4; r++) {
                        int kvloc = c * 16 + g * 4 + r;
                        st_bf(&Pls[w][(m * 16 + fr) * 64 + (kvloc ^ ((fr & 7) << 3))], sf[m][c][r]);
                    }
            bf16x8 pa[2][2];
#pragma unroll
            for (int m = 0; m < 2; m++)
#pragma unroll
                for (int hh = 0; hh < 2; hh++)
                    pa[m][hh] = *(const bf16x8*)&Pls[w][(m * 16 + fr) * 64 + ((hh * 32 + g * 8) ^ ((fr & 7) << 3))];
            __builtin_amdgcn_s_setprio(1);
#pragma unroll
            for (int dt = 0; dt < 8; dt++) {
                const int vrow = dt * 16 + fr;
#pragma unroll
                for (int hh = 0; hh < 2; hh++) {
                    bf16x8 vb = *(const bf16x8*)&Vs[cur][vrow * 64 + (((hh * 4 + g) ^ (vrow & 7)) * 8)];
#pragma unroll
                    for (int m = 0; m < 2; m++)
                        o[m][dt] = __builtin_amdgcn_mfma_f32_16x16x32_bf16(vb, pa[m][hh], o[m][dt], 0, 0, 0);
                }
            }
            __builtin_amdgcn_s_setprio(0);
        }
        __syncthreads();
        cur ^= 1;
    }

    long obase = ((long)b * S_LEN) * DMODEL + (long)h * HDIM;
#pragma unroll
    for (int m = 0; m < 2; m++) {
        const float inv = 1.0f / lrun[m];
        const int q = wrow0 + m * 16 + fr;
#pragma unroll
        for (int dt = 0; dt < 8; dt++)
#pragma unroll
            for (int r = 0; r < 4; r++) {
                int d = dt * 16 + g * 4 + r;
                ctx[obase + (long)q * DMODEL + d] = f2bf(o[m][dt][r] * inv);
            }
    }
}

extern "C" void kernel_launch(void* const* d_in, const int* in_sizes, int n_in,
                              void* d_out, int out_size, void* d_ws, size_t ws_size,
                              hipStream_t stream) {
    const float* hs = (const float*)d_in[0];
    const float* Wq = (const float*)d_in[1];
    const float* Wk = (const float*)d_in[2];
    const float* Wv = (const float*)d_in[3];
    const float* Wo = (const float*)d_in[4];
    float* out = (float*)d_out;

    size_t off = 0;
    char* wsb = (char*)d_ws;
    auto carve = [&](size_t bytes) { void* p = wsb + off; off += bytes; return p; };

    ushort_t* Xb   = (ushort_t*)carve((size_t)M_ROWS * DMODEL * 2);
    ushort_t* Wqb  = (ushort_t*)carve((size_t)DMODEL * DMODEL * 2); // Wq|Wk|Wv contiguous
    ushort_t* Wkb  = (ushort_t*)carve((size_t)DMODEL * DMODEL * 2);
    ushort_t* Wvb  = (ushort_t*)carve((size_t)DMODEL * DMODEL * 2);
    ushort_t* Wob  = (ushort_t*)carve((size_t)DMODEL * DMODEL * 2);
    ushort_t* Qb   = (ushort_t*)carve((size_t)BATCH * NH * S_LEN * HDIM * 2);
    ushort_t* Kb   = (ushort_t*)carve((size_t)BATCH * NH * S_LEN * HDIM * 2);
    ushort_t* Vtb  = (ushort_t*)carve((size_t)BATCH * NH * S_LEN * HDIM * 2);
    ushort_t* ctxb = (ushort_t*)carve((size_t)M_ROWS * DMODEL * 2);
    float* cosT    = (float*)carve((size_t)S_LEN * 64 * 4);
    float* sinT    = (float*)carve((size_t)S_LEN * 64 * 4);

    const int nX = M_ROWS * DMODEL;   // 8388608
    const int nW = DMODEL * DMODEL;   // 4194304

    cvt_bf16<<<(nX / 4) / 256, 256, 0, stream>>>(hs, Xb, nX / 4);
    cvt_bf16<<<(nW / 4) / 256, 256, 0, stream>>>(Wq, Wqb, nW / 4);
    cvt_bf16<<<(nW / 4) / 256, 256, 0, stream>>>(Wk, Wkb, nW / 4);
    cvt_bf16<<<(nW / 4) / 256, 256, 0, stream>>>(Wv, Wvb, nW / 4);
    cvt_bf16<<<(nW / 4) / 256, 256, 0, stream>>>(Wo, Wob, nW / 4);
    rope_tables<<<(S_LEN * 64) / 256, 256, 0, stream>>>(cosT, sinT);

    // Fused QKV projection: A = Xb [4096][2048], B = Wqb..Wvb as [6144][2048].
    // Grid 32*24 = 768 blocks (nwg % 8 == 0 for the XCD grouping).
    gemm8<0><<<(M_ROWS / 128) * (3 * DMODEL / 256), 512, 0, stream>>>(
        Xb, Wqb, Qb, Kb, Vtb, 3 * DMODEL / 256, DMODEL);

    rope_inplace<<<(BATCH * NH * S_LEN * 64) / 256, 256, 0, stream>>>(Qb, Kb, cosT, sinT);

    attn_fwd_v3<<<dim3(S_LEN / 128, BATCH * NH), 256, 0, stream>>>(Qb, Kb, Vtb, ctxb);

    // Output projection: fp32 result straight to d_out. Grid 32*8 = 256 blocks.
    gemm8<2><<<(M_ROWS / 128) * (DMODEL / 256), 512, 0, stream>>>(
        ctxb, Wob, out, nullptr, nullptr, DMODEL / 256, DMODEL);
}

// Round 5
// 300.904 us; speedup vs baseline: 2.1189x; 1.3153x over previous
//
#include <hip/hip_runtime.h>

typedef unsigned short ushort_t;
typedef __bf16 bf16x8 __attribute__((ext_vector_type(8)));
typedef float f32x4 __attribute__((ext_vector_type(4)));

#define S_LEN 2048
#define DMODEL 2048
#define NH 16
#define HDIM 128
#define BATCH 2
#define M_ROWS (BATCH * S_LEN) // 4096

__device__ __forceinline__ ushort_t f2bf(float f) {
    union { float f; unsigned u; } v; v.f = f;
    unsigned r = (v.u + 0x7fffu + ((v.u >> 16) & 1u)) >> 16;
    return (ushort_t)r;
}
__device__ __forceinline__ float bf2f(ushort_t u) {
    union { unsigned u; float f; } v; v.u = ((unsigned)u) << 16;
    return v.f;
}

__device__ __forceinline__ void async16(const void* g, void* l) {
    __builtin_amdgcn_global_load_lds(
        (const __attribute__((address_space(1))) void*)g,
        (__attribute__((address_space(3))) void*)l, 16, 0, 0);
}

// ---------------- fp32 -> bf16 (4 elems/thread) ----------------
__global__ void cvt_bf16(const float* __restrict__ in, ushort_t* __restrict__ out, int n4) {
    int i = blockIdx.x * blockDim.x + threadIdx.x;
    if (i >= n4) return;
    float4 f = ((const float4*)in)[i];
    ushort4 u;
    u.x = f2bf(f.x); u.y = f2bf(f.y); u.z = f2bf(f.z); u.w = f2bf(f.w);
    ((ushort4*)out)[i] = u;
}

// ---------------- RoPE tables [S][64] ----------------
__global__ void rope_tables(float* __restrict__ cosT, float* __restrict__ sinT) {
    int i = blockIdx.x * blockDim.x + threadIdx.x; // 2048*64
    int s = i >> 6, f = i & 63;
    float inv = powf(10000.0f, -(float)(2 * f) / 128.0f);
    float ang = (float)s * inv;
    cosT[i] = cosf(ang);
    sinT[i] = sinf(ang);
}

// ---------------- RoPE in-place on Q and K ([BH][S][HD] bf16) ----------------
__global__ void rope_inplace(ushort_t* __restrict__ Q, ushort_t* __restrict__ K,
                             const float* __restrict__ cosT, const float* __restrict__ sinT) {
    long i = (long)blockIdx.x * blockDim.x + threadIdx.x; // 32*2048*64
    int f = (int)(i & 63);
    long t = i >> 6;
    int s = (int)(t & (S_LEN - 1));
    int bh = (int)(t >> 11);
    long base = ((long)bh * S_LEN + s) * HDIM;
    float c = cosT[s * 64 + f], sn = sinT[s * 64 + f];
    float a0 = bf2f(Q[base + f]), a1 = bf2f(Q[base + 64 + f]);
    Q[base + f]      = f2bf(a0 * c - a1 * sn);
    Q[base + 64 + f] = f2bf(a1 * c + a0 * sn);
    float b0 = bf2f(K[base + f]), b1 = bf2f(K[base + 64 + f]);
    K[base + f]      = f2bf(b0 * c - b1 * sn);
    K[base + 64 + f] = f2bf(b1 * c + b0 * sn);
}

// ================= 8-wave GEMM: BM=128, BN=256, BK=64, 512 threads =================
template <int EPI>
__global__ __launch_bounds__(512) void gemm8(
    const ushort_t* __restrict__ A, const ushort_t* __restrict__ Bm,
    void* __restrict__ C0, void* __restrict__ C1, void* __restrict__ C2,
    int NB, int K) {
    __shared__ __align__(16) ushort_t As[2][128 * 64];
    __shared__ __align__(16) ushort_t Bs[2][256 * 64];
    const int tid = threadIdx.x;
    const int lane = tid & 63;
    const int w = tid >> 6;
    const int wm = w >> 2, wn = w & 3;     // 2 x 4 waves
    const int fr = lane & 15, g = lane >> 4;
    const int nwg = gridDim.x;
    const int work = (blockIdx.x & 7) * (nwg >> 3) + (blockIdx.x >> 3); // XCD grouping
    const int brow = (work / NB) * 128;
    const int bcol = (work % NB) * 256;

    int aRow[2], aK[2], bRow[4], bK[4];
#pragma unroll
    for (int q = 0; q < 2; q++) {
        int d = (q * 512 + tid) * 16;
        int s = d ^ (((d >> 9) & 1) << 5);
        aRow[q] = s >> 7; aK[q] = (s & 127) >> 1;
    }
#pragma unroll
    for (int q = 0; q < 4; q++) {
        int d = (q * 512 + tid) * 16;
        int s = d ^ (((d >> 9) & 1) << 5);
        bRow[q] = s >> 7; bK[q] = (s & 127) >> 1;
    }

    f32x4 acc[4][4];
#pragma unroll
    for (int m = 0; m < 4; m++)
#pragma unroll
        for (int n = 0; n < 4; n++) acc[m][n] = (f32x4){0.f, 0.f, 0.f, 0.f};

    auto stage = [&](int buf, int k0) {
#pragma unroll
        for (int q = 0; q < 2; q++)
            async16(&A[(long)(brow + aRow[q]) * K + k0 + aK[q]], &As[buf][(q * 512 + tid) * 8]);
#pragma unroll
        for (int q = 0; q < 4; q++)
            async16(&Bm[(long)(bcol + bRow[q]) * K + k0 + bK[q]], &Bs[buf][(q * 512 + tid) * 8]);
    };
    auto rdA = [&](int buf, int m, int ks) -> bf16x8 {
        int row = wm * 64 + m * 16 + fr;
        int off = row * 64 + ((ks * 32 + g * 8) ^ (((row >> 2) & 1) << 4));
        return *(const bf16x8*)&As[buf][off];
    };
    auto rdB = [&](int buf, int n, int ks) -> bf16x8 {
        int row = wn * 64 + n * 16 + fr;
        int off = row * 64 + ((ks * 32 + g * 8) ^ (((row >> 2) & 1) << 4));
        return *(const bf16x8*)&Bs[buf][off];
    };

    stage(0, 0);
    __syncthreads();

    const int NT = K / 64;
    int cur = 0;
    for (int kt = 0; kt < NT; ++kt) {
        if (kt + 1 < NT) stage(cur ^ 1, (kt + 1) * 64);
        bf16x8 a0[2][2], a2[2][2], bn[4][2];
#pragma unroll
        for (int m = 0; m < 2; m++)
#pragma unroll
            for (int ks = 0; ks < 2; ks++) a0[m][ks] = rdA(cur, m, ks);
#pragma unroll
        for (int n = 0; n < 2; n++)
#pragma unroll
            for (int ks = 0; ks < 2; ks++) bn[n][ks] = rdB(cur, n, ks);
        __builtin_amdgcn_s_setprio(1);
#pragma unroll
        for (int m = 0; m < 2; m++)
#pragma unroll
            for (int n = 0; n < 2; n++)
#pragma unroll
                for (int ks = 0; ks < 2; ks++)
                    acc[m][n] = __builtin_amdgcn_mfma_f32_16x16x32_bf16(a0[m][ks], bn[n][ks], acc[m][n], 0, 0, 0);
        __builtin_amdgcn_s_setprio(0);
#pragma unroll
        for (int n = 2; n < 4; n++)
#pragma unroll
            for (int ks = 0; ks < 2; ks++) bn[n][ks] = rdB(cur, n, ks);
        __builtin_amdgcn_s_setprio(1);
#pragma unroll
        for (int m = 0; m < 2; m++)
#pragma unroll
            for (int n = 2; n < 4; n++)
#pragma unroll
                for (int ks = 0; ks < 2; ks++)
                    acc[m][n] = __builtin_amdgcn_mfma_f32_16x16x32_bf16(a0[m][ks], bn[n][ks], acc[m][n], 0, 0, 0);
        __builtin_amdgcn_s_setprio(0);
#pragma unroll
        for (int m = 0; m < 2; m++)
#pragma unroll
            for (int ks = 0; ks < 2; ks++) a2[m][ks] = rdA(cur, m + 2, ks);
        __builtin_amdgcn_s_setprio(1);
#pragma unroll
        for (int m = 0; m < 2; m++)
#pragma unroll
            for (int n = 2; n < 4; n++)
#pragma unroll
                for (int ks = 0; ks < 2; ks++)
                    acc[m + 2][n] = __builtin_amdgcn_mfma_f32_16x16x32_bf16(a2[m][ks], bn[n][ks], acc[m + 2][n], 0, 0, 0);
        __builtin_amdgcn_s_setprio(0);
        __builtin_amdgcn_s_setprio(1);
#pragma unroll
        for (int m = 0; m < 2; m++)
#pragma unroll
            for (int n = 0; n < 2; n++)
#pragma unroll
                for (int ks = 0; ks < 2; ks++)
                    acc[m + 2][n] = __builtin_amdgcn_mfma_f32_16x16x32_bf16(a2[m][ks], bn[n][ks], acc[m + 2][n], 0, 0, 0);
        __builtin_amdgcn_s_setprio(0);
        __syncthreads();
        cur ^= 1;
    }

    const int rbase = brow + wm * 64;
    if constexpr (EPI == 0) {
        const int proj = bcol >> 11; // 0=Q, 1=K, 2=V
        const int cbase = (bcol & 2047) + wn * 64;
        if (proj < 2) {
            ushort_t* dst = (ushort_t*)(proj == 0 ? C0 : C1);
#pragma unroll
            for (int m = 0; m < 4; m++)
#pragma unroll
                for (int n = 0; n < 4; n++) {
                    int c2 = cbase + n * 16 + fr;
                    int h = c2 >> 7, hd = c2 & 127;
#pragma unroll
                    for (int r = 0; r < 4; r++) {
                        int row = rbase + m * 16 + g * 4 + r;
                        int b = row >> 11, s = row & (S_LEN - 1);
                        dst[(((long)(b * NH + h) * S_LEN) + s) * HDIM + hd] = f2bf(acc[m][n][r]);
                    }
                }
        } else {
            ushort_t* dst = (ushort_t*)C2;
#pragma unroll
            for (int m = 0; m < 4; m++) {
                int row0 = rbase + m * 16 + g * 4;
                int b = row0 >> 11, s0 = row0 & (S_LEN - 1);
#pragma unroll
                for (int n = 0; n < 4; n++) {
                    int c2 = cbase + n * 16 + fr;
                    int h = c2 >> 7, hd = c2 & 127;
                    ushort4 u;
                    u.x = f2bf(acc[m][n][0]); u.y = f2bf(acc[m][n][1]);
                    u.z = f2bf(acc[m][n][2]); u.w = f2bf(acc[m][n][3]);
                    *(ushort4*)&dst[(((long)(b * NH + h) * HDIM) + hd) * S_LEN + s0] = u;
                }
            }
        }
    } else {
        float* dst = (float*)C0;
#pragma unroll
        for (int m = 0; m < 4; m++)
#pragma unroll
            for (int n = 0; n < 4; n++) {
                int col = bcol + wn * 64 + n * 16 + fr;
#pragma unroll
                for (int r = 0; r < 4; r++) {
                    int row = rbase + m * 16 + g * 4 + r;
                    dst[(long)row * DMODEL + col] = acc[m][n][r];
                }
            }
    }
}

// ---------------- Flash attention v4: uniform work pairing ----------
// Each block: 4 waves x 16 q-rows = 64-row q-tile; processes the PAIR of q-tiles
// (qt = p, qt = 31-p) sequentially -> every block does exactly 33 KV-tile units.
// bid decode puts all pair-blocks of a head on one XCD (K/V L2-resident).
// Swapped QK^T (lane owns a kv-slice of ONE q-row), b64-packed P bounce.
__global__ __launch_bounds__(256) void attn_fwd_v4(
    const ushort_t* __restrict__ Q, const ushort_t* __restrict__ K,
    const ushort_t* __restrict__ Vt, ushort_t* __restrict__ ctx) {
    __shared__ __align__(16) ushort_t Ks[2][64 * 128];
    __shared__ __align__(16) ushort_t Vs[2][128 * 64];
    __shared__ __align__(16) ushort_t Pls[4][16 * 64];

    const int tid = threadIdx.x;
    const int lane = tid & 63;
    const int w = tid >> 6;
    const int g = lane >> 4;
    const int fr = lane & 15;
    const int fk = g * 8;

    const int bid = blockIdx.x;              // 512 blocks
    const int xcd = bid & 7;
    const int t6 = bid >> 3;                 // 0..63
    const int bh = xcd + 8 * (t6 & 3);       // 4 heads per XCD
    const int p = t6 >> 2;                   // 0..15 pair index
    const int qtA = p, qtB = 31 - p;
    const int b = bh >> 4, h = bh & 15;

    const ushort_t* Qb = Q + (long)bh * S_LEN * HDIM;
    const ushort_t* Kb = K + (long)bh * S_LEN * HDIM;
    const ushort_t* Vb = Vt + (long)bh * HDIM * S_LEN;

    int koff[4], voff[4], kdst[4], vdst[4];
#pragma unroll
    for (int r = 0; r < 4; r++) {
        int ci = r * 256 + tid;
        int krow = ci >> 4, kwc = ci & 15;
        koff[r] = krow * HDIM + ((kwc ^ (krow & 7)) * 8);
        kdst[r] = ci * 8;
        int vrow = ci >> 3, vwc = ci & 7;
        voff[r] = vrow * S_LEN + ((vwc ^ (vrow & 7)) * 8);
        vdst[r] = ci * 8;
    }
    auto stage = [&](int buf, int kv0) {
        const ushort_t* Kg = Kb + (long)kv0 * HDIM;
        const ushort_t* Vg = Vb + kv0;
#pragma unroll
        for (int r = 0; r < 4; r++) async16(Kg + koff[r], &Ks[buf][kdst[r]]);
#pragma unroll
        for (int r = 0; r < 4; r++) async16(Vg + voff[r], &Vs[buf][vdst[r]]);
    };

    int qrow0 = qtA * 64 + w * 16;
    bf16x8 qf[4];
    auto loadQ = [&]() {
#pragma unroll
        for (int t = 0; t < 4; t++)
            qf[t] = *(const bf16x8*)&Qb[(long)(qrow0 + fr) * HDIM + t * 32 + fk];
    };
    loadQ();

    f32x4 o[8];
#pragma unroll
    for (int i = 0; i < 8; i++) o[i] = (f32x4){0.f, 0.f, 0.f, 0.f};
    float mrun = -1e30f, lrun = 0.f;

    const float scale = 0.08838834764831845f; // 1/sqrt(128)
    long obase = ((long)b * S_LEN) * DMODEL + (long)h * HDIM;
    auto flush = [&]() {
        float inv = 1.0f / lrun;
        long rowb = obase + (long)(qrow0 + fr) * DMODEL;
#pragma unroll
        for (int dt = 0; dt < 8; dt++) {
            ushort4 u;
            u.x = f2bf(o[dt][0] * inv); u.y = f2bf(o[dt][1] * inv);
            u.z = f2bf(o[dt][2] * inv); u.w = f2bf(o[dt][3] * inv);
            *(ushort4*)&ctx[rowb + dt * 16 + g * 4] = u;
        }
    };

    const int ntA = qtA + 1;
    const int ntot = 33; // ntA + (qtB+1) = 33 for every block

    stage(0, 0);
    __syncthreads();

    int cur = 0;
    for (int u = 0; u < ntot; ++u) {
        if (u + 1 < ntot) {
            int kvn = (u + 1 < ntA) ? (u + 1) : (u + 1 - ntA);
            stage(cur ^ 1, kvn * 64);
        }
        const int kv0 = ((u < ntA) ? u : (u - ntA)) * 64;
        if (u == ntA) { // phase switch A -> B
            flush();
            qrow0 = qtB * 64 + w * 16;
            loadQ();
#pragma unroll
            for (int i = 0; i < 8; i++) o[i] = (f32x4){0.f, 0.f, 0.f, 0.f};
            mrun = -1e30f; lrun = 0.f;
        }
        if (kv0 <= qrow0 + 15) {
            // ---- QK^T (swapped: A=K rows=kv, B=Q cols=q) ----
            f32x4 sf[4]; // [c]: kv = kv0+c*16+g*4+r, q = qrow0+fr
#pragma unroll
            for (int c = 0; c < 4; c++) sf[c] = (f32x4){0.f, 0.f, 0.f, 0.f};
            __builtin_amdgcn_s_setprio(1);
#pragma unroll
            for (int c = 0; c < 4; c++) {
                const int krow = c * 16 + fr;
#pragma unroll
                for (int tt = 0; tt < 4; tt++) {
                    bf16x8 kb = *(const bf16x8*)&Ks[cur][krow * 128 + (((tt * 4 + g) ^ (krow & 7)) * 8)];
                    sf[c] = __builtin_amdgcn_mfma_f32_16x16x32_bf16(kb, qf[tt], sf[c], 0, 0, 0);
                }
            }
            __builtin_amdgcn_s_setprio(0);
            // ---- scale + causal mask ----
            if (kv0 + 63 <= qrow0) {
#pragma unroll
                for (int c = 0; c < 4; c++)
#pragma unroll
                    for (int r = 0; r < 4; r++) sf[c][r] *= scale;
            } else {
                const int q = qrow0 + fr;
#pragma unroll
                for (int c = 0; c < 4; c++)
#pragma unroll
                    for (int r = 0; r < 4; r++) {
                        int kv = kv0 + c * 16 + g * 4 + r;
                        sf[c][r] = (kv <= q) ? sf[c][r] * scale : -1e30f;
                    }
            }
            // ---- online softmax (lane owns 16 kv of its q-row) ----
            {
                float vmax = -1e30f;
#pragma unroll
                for (int c = 0; c < 4; c++) {
                    float t0 = fmaxf(fmaxf(sf[c][0], sf[c][1]), fmaxf(sf[c][2], sf[c][3]));
                    vmax = fmaxf(vmax, t0);
                }
                vmax = fmaxf(vmax, __shfl_xor(vmax, 16));
                vmax = fmaxf(vmax, __shfl_xor(vmax, 32));
                if (!__all(vmax - mrun <= 8.f)) { // defer-max
                    float nm = fmaxf(mrun, vmax);
                    float alpha = __expf(mrun - nm);
                    mrun = nm;
                    lrun *= alpha;
#pragma unroll
                    for (int dt = 0; dt < 8; dt++) o[dt] *= alpha;
                }
                float rs = 0.f;
#pragma unroll
                for (int c = 0; c < 4; c++)
#pragma unroll
                    for (int r = 0; r < 4; r++) {
                        float pv = __expf(sf[c][r] - mrun);
                        sf[c][r] = pv;
                        rs += pv;
                    }
                rs += __shfl_xor(rs, 16);
                rs += __shfl_xor(rs, 32);
                lrun += rs;
            }
            // ---- P -> LDS [q=16][kv=64], b64-packed, XOR-swizzled ----
#pragma unroll
            for (int c = 0; c < 4; c++) {
                ushort4 u;
                u.x = f2bf(sf[c][0]); u.y = f2bf(sf[c][1]);
                u.z = f2bf(sf[c][2]); u.w = f2bf(sf[c][3]);
                *(ushort4*)&Pls[w][fr * 64 + ((c * 16 + g * 4) ^ ((fr & 7) << 3))] = u;
            }
            bf16x8 pa[2]; // B-frag: P[kv=hh*32+g*8+j][q=fr]
#pragma unroll
            for (int hh = 0; hh < 2; hh++)
                pa[hh] = *(const bf16x8*)&Pls[w][fr * 64 + ((hh * 32 + g * 8) ^ ((fr & 7) << 3))];
            // ---- PV: o = mfma(A=V^T rows=d, B=P cols=q) ----
            __builtin_amdgcn_s_setprio(1);
#pragma unroll
            for (int dt = 0; dt < 8; dt++) {
                const int vrow = dt * 16 + fr;
#pragma unroll
                for (int hh = 0; hh < 2; hh++) {
                    bf16x8 vb = *(const bf16x8*)&Vs[cur][vrow * 64 + (((hh * 4 + g) ^ (vrow & 7)) * 8)];
                    o[dt] = __builtin_amdgcn_mfma_f32_16x16x32_bf16(vb, pa[hh], o[dt], 0, 0, 0);
                }
            }
            __builtin_amdgcn_s_setprio(0);
        }
        __syncthreads();
        cur ^= 1;
    }
    flush();
}

extern "C" void kernel_launch(void* const* d_in, const int* in_sizes, int n_in,
                              void* d_out, int out_size, void* d_ws, size_t ws_size,
                              hipStream_t stream) {
    const float* hs = (const float*)d_in[0];
    const float* Wq = (const float*)d_in[1];
    const float* Wk = (const float*)d_in[2];
    const float* Wv = (const float*)d_in[3];
    const float* Wo = (const float*)d_in[4];
    float* out = (float*)d_out;

    size_t off = 0;
    char* wsb = (char*)d_ws;
    auto carve = [&](size_t bytes) { void* p = wsb + off; off += bytes; return p; };

    ushort_t* Xb   = (ushort_t*)carve((size_t)M_ROWS * DMODEL * 2);
    ushort_t* Wqb  = (ushort_t*)carve((size_t)DMODEL * DMODEL * 2); // Wq|Wk|Wv contiguous
    ushort_t* Wkb  = (ushort_t*)carve((size_t)DMODEL * DMODEL * 2);
    ushort_t* Wvb  = (ushort_t*)carve((size_t)DMODEL * DMODEL * 2);
    ushort_t* Wob  = (ushort_t*)carve((size_t)DMODEL * DMODEL * 2);
    ushort_t* Qb   = (ushort_t*)carve((size_t)BATCH * NH * S_LEN * HDIM * 2);
    ushort_t* Kb   = (ushort_t*)carve((size_t)BATCH * NH * S_LEN * HDIM * 2);
    ushort_t* Vtb  = (ushort_t*)carve((size_t)BATCH * NH * S_LEN * HDIM * 2);
    ushort_t* ctxb = (ushort_t*)carve((size_t)M_ROWS * DMODEL * 2);
    float* cosT    = (float*)carve((size_t)S_LEN * 64 * 4);
    float* sinT    = (float*)carve((size_t)S_LEN * 64 * 4);

    const int nX = M_ROWS * DMODEL;   // 8388608
    const int nW = DMODEL * DMODEL;   // 4194304

    cvt_bf16<<<(nX / 4) / 256, 256, 0, stream>>>(hs, Xb, nX / 4);
    cvt_bf16<<<(nW / 4) / 256, 256, 0, stream>>>(Wq, Wqb, nW / 4);
    cvt_bf16<<<(nW / 4) / 256, 256, 0, stream>>>(Wk, Wkb, nW / 4);
    cvt_bf16<<<(nW / 4) / 256, 256, 0, stream>>>(Wv, Wvb, nW / 4);
    cvt_bf16<<<(nW / 4) / 256, 256, 0, stream>>>(Wo, Wob, nW / 4);
    rope_tables<<<(S_LEN * 64) / 256, 256, 0, stream>>>(cosT, sinT);

    // Fused QKV projection: A = Xb [4096][2048], B = Wqb..Wvb as [6144][2048].
    gemm8<0><<<(M_ROWS / 128) * (3 * DMODEL / 256), 512, 0, stream>>>(
        Xb, Wqb, Qb, Kb, Vtb, 3 * DMODEL / 256, DMODEL);

    rope_inplace<<<(BATCH * NH * S_LEN * 64) / 256, 256, 0, stream>>>(Qb, Kb, cosT, sinT);

    attn_fwd_v4<<<512, 256, 0, stream>>>(Qb, Kb, Vtb, ctxb);

    // Output projection: fp32 result straight to d_out.
    gemm8<2><<<(M_ROWS / 128) * (DMODEL / 256), 512, 0, stream>>>(
        ctxb, Wob, out, nullptr, nullptr, DMODEL / 256, DMODEL);
}

// Round 6
// 294.688 us; speedup vs baseline: 2.1636x; 1.0211x over previous
//
#include <hip/hip_runtime.h>

typedef unsigned short ushort_t;
typedef __bf16 bf16x8 __attribute__((ext_vector_type(8)));
typedef float f32x4 __attribute__((ext_vector_type(4)));

#define S_LEN 2048
#define DMODEL 2048
#define NH 16
#define HDIM 128
#define BATCH 2
#define M_ROWS (BATCH * S_LEN) // 4096

__device__ __forceinline__ ushort_t f2bf(float f) {
    union { float f; unsigned u; } v; v.f = f;
    unsigned r = (v.u + 0x7fffu + ((v.u >> 16) & 1u)) >> 16;
    return (ushort_t)r;
}
__device__ __forceinline__ float bf2f(ushort_t u) {
    union { unsigned u; float f; } v; v.u = ((unsigned)u) << 16;
    return v.f;
}

__device__ __forceinline__ void async16(const void* g, void* l) {
    __builtin_amdgcn_global_load_lds(
        (const __attribute__((address_space(1))) void*)g,
        (__attribute__((address_space(3))) void*)l, 16, 0, 0);
}

// ---------------- fp32 -> bf16 (4 elems/thread) ----------------
__global__ void cvt_bf16(const float* __restrict__ in, ushort_t* __restrict__ out, int n4) {
    int i = blockIdx.x * blockDim.x + threadIdx.x;
    if (i >= n4) return;
    float4 f = ((const float4*)in)[i];
    ushort4 u;
    u.x = f2bf(f.x); u.y = f2bf(f.y); u.z = f2bf(f.z); u.w = f2bf(f.w);
    ((ushort4*)out)[i] = u;
}

// ---------------- RoPE tables [S][64] ----------------
__global__ void rope_tables(float* __restrict__ cosT, float* __restrict__ sinT) {
    int i = blockIdx.x * blockDim.x + threadIdx.x; // 2048*64
    int s = i >> 6, f = i & 63;
    float inv = powf(10000.0f, -(float)(2 * f) / 128.0f);
    float ang = (float)s * inv;
    cosT[i] = cosf(ang);
    sinT[i] = sinf(ang);
}

// ---------------- RoPE in-place on Q and K ([BH][S][HD] bf16) ----------------
__global__ void rope_inplace(ushort_t* __restrict__ Q, ushort_t* __restrict__ K,
                             const float* __restrict__ cosT, const float* __restrict__ sinT) {
    long i = (long)blockIdx.x * blockDim.x + threadIdx.x; // 32*2048*64
    int f = (int)(i & 63);
    long t = i >> 6;
    int s = (int)(t & (S_LEN - 1));
    int bh = (int)(t >> 11);
    long base = ((long)bh * S_LEN + s) * HDIM;
    float c = cosT[s * 64 + f], sn = sinT[s * 64 + f];
    float a0 = bf2f(Q[base + f]), a1 = bf2f(Q[base + 64 + f]);
    Q[base + f]      = f2bf(a0 * c - a1 * sn);
    Q[base + 64 + f] = f2bf(a1 * c + a0 * sn);
    float b0 = bf2f(K[base + f]), b1 = bf2f(K[base + 64 + f]);
    K[base + f]      = f2bf(b0 * c - b1 * sn);
    K[base + 64 + f] = f2bf(b1 * c + b0 * sn);
}

// ================= 8-wave GEMM: BM=128, BN=256, BK=64, 512 threads =================
// 3-bit XOR swizzle (byte ^= (row&7)<<4, involution pre-applied to global src),
// XCD-owns-a-B-column-slice decode, counted-vmcnt 2-deep pipeline (no vmcnt(0)
// drain in the main loop).
template <int EPI>
__global__ __launch_bounds__(512) void gemm8(
    const ushort_t* __restrict__ A, const ushort_t* __restrict__ Bm,
    void* __restrict__ C0, void* __restrict__ C1, void* __restrict__ C2,
    int NB, int K) {
    __shared__ __align__(16) ushort_t As[2][128 * 64];
    __shared__ __align__(16) ushort_t Bs[2][256 * 64];
    const int tid = threadIdx.x;
    const int lane = tid & 63;
    const int w = tid >> 6;
    const int wm = w >> 2, wn = w & 3;     // 2 x 4 waves
    const int fr = lane & 15, g = lane >> 4;
    // XCD c owns B col-blocks [c*cpx, (c+1)*cpx); iterate row-major within.
    const int cpx = NB >> 3;
    const int xcd = blockIdx.x & 7;
    const int local = blockIdx.x >> 3;
    const int brow = (local / cpx) * 128;
    const int bcol = (xcd * cpx + local % cpx) * 256;

    // staging: pre-swizzled source coords (A: 2 rounds of 8KB, B: 4 rounds)
    int aRow[2], aK[2], bRow[4], bK[4];
#pragma unroll
    for (int q = 0; q < 2; q++) {
        int d = (q * 512 + tid) * 16;      // linear LDS dest byte
        int row = d >> 7;
        int s = d ^ ((row & 7) << 4);      // involutive source swizzle
        aRow[q] = row; aK[q] = (s & 127) >> 1;
    }
#pragma unroll
    for (int q = 0; q < 4; q++) {
        int d = (q * 512 + tid) * 16;
        int row = d >> 7;
        int s = d ^ ((row & 7) << 4);
        bRow[q] = row; bK[q] = (s & 127) >> 1;
    }

    f32x4 acc[4][4];
#pragma unroll
    for (int m = 0; m < 4; m++)
#pragma unroll
        for (int n = 0; n < 4; n++) acc[m][n] = (f32x4){0.f, 0.f, 0.f, 0.f};

    auto stage = [&](int buf, int k0) {
#pragma unroll
        for (int q = 0; q < 2; q++)
            async16(&A[(long)(brow + aRow[q]) * K + k0 + aK[q]], &As[buf][(q * 512 + tid) * 8]);
#pragma unroll
        for (int q = 0; q < 4; q++)
            async16(&Bm[(long)(bcol + bRow[q]) * K + k0 + bK[q]], &Bs[buf][(q * 512 + tid) * 8]);
    };
    auto rdA = [&](int buf, int m, int ks) -> bf16x8 {
        int row = wm * 64 + m * 16 + fr;
        int cb = (ks * 64 + g * 16) ^ ((row & 7) << 4);
        return *(const bf16x8*)((const char*)&As[buf][0] + row * 128 + cb);
    };
    auto rdB = [&](int buf, int n, int ks) -> bf16x8 {
        int row = wn * 64 + n * 16 + fr;
        int cb = (ks * 64 + g * 16) ^ ((row & 7) << 4);
        return *(const bf16x8*)((const char*)&Bs[buf][0] + row * 128 + cb);
    };

    const int NT = K / 64;
    stage(0, 0);
    stage(1, 64);

    for (int kt = 0; kt < NT; ++kt) {
        const int cur = kt & 1;
        if (kt + 1 < NT) {
            asm volatile("s_waitcnt vmcnt(6)" ::: "memory");
        } else {
            asm volatile("s_waitcnt vmcnt(0)" ::: "memory");
        }
        __builtin_amdgcn_sched_barrier(0);
        __builtin_amdgcn_s_barrier();
        __builtin_amdgcn_sched_barrier(0);

        bf16x8 a0[2][2], a2[2][2], bn[4][2];
#pragma unroll
        for (int m = 0; m < 2; m++)
#pragma unroll
            for (int ks = 0; ks < 2; ks++) a0[m][ks] = rdA(cur, m, ks);
#pragma unroll
        for (int n = 0; n < 2; n++)
#pragma unroll
            for (int ks = 0; ks < 2; ks++) bn[n][ks] = rdB(cur, n, ks);
        __builtin_amdgcn_s_setprio(1);
#pragma unroll
        for (int m = 0; m < 2; m++)
#pragma unroll
            for (int n = 0; n < 2; n++)
#pragma unroll
                for (int ks = 0; ks < 2; ks++)
                    acc[m][n] = __builtin_amdgcn_mfma_f32_16x16x32_bf16(a0[m][ks], bn[n][ks], acc[m][n], 0, 0, 0);
        __builtin_amdgcn_s_setprio(0);
#pragma unroll
        for (int n = 2; n < 4; n++)
#pragma unroll
            for (int ks = 0; ks < 2; ks++) bn[n][ks] = rdB(cur, n, ks);
        __builtin_amdgcn_s_setprio(1);
#pragma unroll
        for (int m = 0; m < 2; m++)
#pragma unroll
            for (int n = 2; n < 4; n++)
#pragma unroll
                for (int ks = 0; ks < 2; ks++)
                    acc[m][n] = __builtin_amdgcn_mfma_f32_16x16x32_bf16(a0[m][ks], bn[n][ks], acc[m][n], 0, 0, 0);
        __builtin_amdgcn_s_setprio(0);
#pragma unroll
        for (int m = 0; m < 2; m++)
#pragma unroll
            for (int ks = 0; ks < 2; ks++) a2[m][ks] = rdA(cur, m + 2, ks);
        __builtin_amdgcn_s_setprio(1);
#pragma unroll
        for (int m = 0; m < 2; m++)
#pragma unroll
            for (int n = 2; n < 4; n++)
#pragma unroll
                for (int ks = 0; ks < 2; ks++)
                    acc[m + 2][n] = __builtin_amdgcn_mfma_f32_16x16x32_bf16(a2[m][ks], bn[n][ks], acc[m + 2][n], 0, 0, 0);
        __builtin_amdgcn_s_setprio(0);
        __builtin_amdgcn_s_setprio(1);
#pragma unroll
        for (int m = 0; m < 2; m++)
#pragma unroll
            for (int n = 0; n < 2; n++)
#pragma unroll
                for (int ks = 0; ks < 2; ks++)
                    acc[m + 2][n] = __builtin_amdgcn_mfma_f32_16x16x32_bf16(a2[m][ks], bn[n][ks], acc[m + 2][n], 0, 0, 0);
        __builtin_amdgcn_s_setprio(0);

        __builtin_amdgcn_s_barrier();   // all waves done reading buf cur
        __builtin_amdgcn_sched_barrier(0);
        if (kt + 2 < NT) stage(cur, (kt + 2) * 64);
    }

    const int rbase = brow + wm * 64;
    if constexpr (EPI == 0) {
        const int proj = bcol >> 11; // 0=Q, 1=K, 2=V
        const int cbase = (bcol & 2047) + wn * 64;
        if (proj < 2) {
            ushort_t* dst = (ushort_t*)(proj == 0 ? C0 : C1);
#pragma unroll
            for (int m = 0; m < 4; m++)
#pragma unroll
                for (int n = 0; n < 4; n++) {
                    int c2 = cbase + n * 16 + fr;
                    int h = c2 >> 7, hd = c2 & 127;
#pragma unroll
                    for (int r = 0; r < 4; r++) {
                        int row = rbase + m * 16 + g * 4 + r;
                        int b = row >> 11, s = row & (S_LEN - 1);
                        dst[(((long)(b * NH + h) * S_LEN) + s) * HDIM + hd] = f2bf(acc[m][n][r]);
                    }
                }
        } else {
            ushort_t* dst = (ushort_t*)C2;
#pragma unroll
            for (int m = 0; m < 4; m++) {
                int row0 = rbase + m * 16 + g * 4;
                int b = row0 >> 11, s0 = row0 & (S_LEN - 1);
#pragma unroll
                for (int n = 0; n < 4; n++) {
                    int c2 = cbase + n * 16 + fr;
                    int h = c2 >> 7, hd = c2 & 127;
                    ushort4 u;
                    u.x = f2bf(acc[m][n][0]); u.y = f2bf(acc[m][n][1]);
                    u.z = f2bf(acc[m][n][2]); u.w = f2bf(acc[m][n][3]);
                    *(ushort4*)&dst[(((long)(b * NH + h) * HDIM) + hd) * S_LEN + s0] = u;
                }
            }
        }
    } else {
        float* dst = (float*)C0;
#pragma unroll
        for (int m = 0; m < 4; m++)
#pragma unroll
            for (int n = 0; n < 4; n++) {
                int col = bcol + wn * 64 + n * 16 + fr;
#pragma unroll
                for (int r = 0; r < 4; r++) {
                    int row = rbase + m * 16 + g * 4 + r;
                    dst[(long)row * DMODEL + col] = acc[m][n][r];
                }
            }
    }
}

// ---------------- Flash attention v4: uniform work pairing ----------
__global__ __launch_bounds__(256) void attn_fwd_v4(
    const ushort_t* __restrict__ Q, const ushort_t* __restrict__ K,
    const ushort_t* __restrict__ Vt, ushort_t* __restrict__ ctx) {
    __shared__ __align__(16) ushort_t Ks[2][64 * 128];
    __shared__ __align__(16) ushort_t Vs[2][128 * 64];
    __shared__ __align__(16) ushort_t Pls[4][16 * 64];

    const int tid = threadIdx.x;
    const int lane = tid & 63;
    const int w = tid >> 6;
    const int g = lane >> 4;
    const int fr = lane & 15;
    const int fk = g * 8;

    const int bid = blockIdx.x;              // 512 blocks
    const int xcd = bid & 7;
    const int t6 = bid >> 3;                 // 0..63
    const int bh = xcd + 8 * (t6 & 3);       // 4 heads per XCD
    const int p = t6 >> 2;                   // 0..15 pair index
    const int qtA = p, qtB = 31 - p;
    const int b = bh >> 4, h = bh & 15;

    const ushort_t* Qb = Q + (long)bh * S_LEN * HDIM;
    const ushort_t* Kb = K + (long)bh * S_LEN * HDIM;
    const ushort_t* Vb = Vt + (long)bh * HDIM * S_LEN;

    int koff[4], voff[4], kdst[4], vdst[4];
#pragma unroll
    for (int r = 0; r < 4; r++) {
        int ci = r * 256 + tid;
        int krow = ci >> 4, kwc = ci & 15;
        koff[r] = krow * HDIM + ((kwc ^ (krow & 7)) * 8);
        kdst[r] = ci * 8;
        int vrow = ci >> 3, vwc = ci & 7;
        voff[r] = vrow * S_LEN + ((vwc ^ (vrow & 7)) * 8);
        vdst[r] = ci * 8;
    }
    auto stage = [&](int buf, int kv0) {
        const ushort_t* Kg = Kb + (long)kv0 * HDIM;
        const ushort_t* Vg = Vb + kv0;
#pragma unroll
        for (int r = 0; r < 4; r++) async16(Kg + koff[r], &Ks[buf][kdst[r]]);
#pragma unroll
        for (int r = 0; r < 4; r++) async16(Vg + voff[r], &Vs[buf][vdst[r]]);
    };

    int qrow0 = qtA * 64 + w * 16;
    bf16x8 qf[4];
    auto loadQ = [&]() {
#pragma unroll
        for (int t = 0; t < 4; t++)
            qf[t] = *(const bf16x8*)&Qb[(long)(qrow0 + fr) * HDIM + t * 32 + fk];
    };
    loadQ();

    f32x4 o[8];
#pragma unroll
    for (int i = 0; i < 8; i++) o[i] = (f32x4){0.f, 0.f, 0.f, 0.f};
    float mrun = -1e30f, lrun = 0.f;

    const float scale = 0.08838834764831845f; // 1/sqrt(128)
    long obase = ((long)b * S_LEN) * DMODEL + (long)h * HDIM;
    auto flush = [&]() {
        float inv = 1.0f / lrun;
        long rowb = obase + (long)(qrow0 + fr) * DMODEL;
#pragma unroll
        for (int dt = 0; dt < 8; dt++) {
            ushort4 u;
            u.x = f2bf(o[dt][0] * inv); u.y = f2bf(o[dt][1] * inv);
            u.z = f2bf(o[dt][2] * inv); u.w = f2bf(o[dt][3] * inv);
            *(ushort4*)&ctx[rowb + dt * 16 + g * 4] = u;
        }
    };

    const int ntA = qtA + 1;
    const int ntot = 33; // ntA + (qtB+1) = 33 for every block

    stage(0, 0);
    __syncthreads();

    int cur = 0;
    for (int u = 0; u < ntot; ++u) {
        if (u + 1 < ntot) {
            int kvn = (u + 1 < ntA) ? (u + 1) : (u + 1 - ntA);
            stage(cur ^ 1, kvn * 64);
        }
        const int kv0 = ((u < ntA) ? u : (u - ntA)) * 64;
        if (u == ntA) { // phase switch A -> B
            flush();
            qrow0 = qtB * 64 + w * 16;
            loadQ();
#pragma unroll
            for (int i = 0; i < 8; i++) o[i] = (f32x4){0.f, 0.f, 0.f, 0.f};
            mrun = -1e30f; lrun = 0.f;
        }
        if (kv0 <= qrow0 + 15) {
            // ---- QK^T (swapped: A=K rows=kv, B=Q cols=q) ----
            f32x4 sf[4]; // [c]: kv = kv0+c*16+g*4+r, q = qrow0+fr
#pragma unroll
            for (int c = 0; c < 4; c++) sf[c] = (f32x4){0.f, 0.f, 0.f, 0.f};
            __builtin_amdgcn_s_setprio(1);
#pragma unroll
            for (int c = 0; c < 4; c++) {
                const int krow = c * 16 + fr;
#pragma unroll
                for (int tt = 0; tt < 4; tt++) {
                    bf16x8 kb = *(const bf16x8*)&Ks[cur][krow * 128 + (((tt * 4 + g) ^ (krow & 7)) * 8)];
                    sf[c] = __builtin_amdgcn_mfma_f32_16x16x32_bf16(kb, qf[tt], sf[c], 0, 0, 0);
                }
            }
            __builtin_amdgcn_s_setprio(0);
            // ---- scale + causal mask ----
            if (kv0 + 63 <= qrow0) {
#pragma unroll
                for (int c = 0; c < 4; c++)
#pragma unroll
                    for (int r = 0; r < 4; r++) sf[c][r] *= scale;
            } else {
                const int q = qrow0 + fr;
#pragma unroll
                for (int c = 0; c < 4; c++)
#pragma unroll
                    for (int r = 0; r < 4; r++) {
                        int kv = kv0 + c * 16 + g * 4 + r;
                        sf[c][r] = (kv <= q) ? sf[c][r] * scale : -1e30f;
                    }
            }
            // ---- online softmax (lane owns 16 kv of its q-row) ----
            {
                float vmax = -1e30f;
#pragma unroll
                for (int c = 0; c < 4; c++) {
                    float t0 = fmaxf(fmaxf(sf[c][0], sf[c][1]), fmaxf(sf[c][2], sf[c][3]));
                    vmax = fmaxf(vmax, t0);
                }
                vmax = fmaxf(vmax, __shfl_xor(vmax, 16));
                vmax = fmaxf(vmax, __shfl_xor(vmax, 32));
                if (!__all(vmax - mrun <= 8.f)) { // defer-max
                    float nm = fmaxf(mrun, vmax);
                    float alpha = __expf(mrun - nm);
                    mrun = nm;
                    lrun *= alpha;
#pragma unroll
                    for (int dt = 0; dt < 8; dt++) o[dt] *= alpha;
                }
                float rs = 0.f;
#pragma unroll
                for (int c = 0; c < 4; c++)
#pragma unroll
                    for (int r = 0; r < 4; r++) {
                        float pv = __expf(sf[c][r] - mrun);
                        sf[c][r] = pv;
                        rs += pv;
                    }
                rs += __shfl_xor(rs, 16);
                rs += __shfl_xor(rs, 32);
                lrun += rs;
            }
            // ---- P -> LDS [q=16][kv=64], b64-packed, XOR-swizzled ----
#pragma unroll
            for (int c = 0; c < 4; c++) {
                ushort4 u;
                u.x = f2bf(sf[c][0]); u.y = f2bf(sf[c][1]);
                u.z = f2bf(sf[c][2]); u.w = f2bf(sf[c][3]);
                *(ushort4*)&Pls[w][fr * 64 + ((c * 16 + g * 4) ^ ((fr & 7) << 3))] = u;
            }
            bf16x8 pa[2]; // B-frag: P[kv=hh*32+g*8+j][q=fr]
#pragma unroll
            for (int hh = 0; hh < 2; hh++)
                pa[hh] = *(const bf16x8*)&Pls[w][fr * 64 + ((hh * 32 + g * 8) ^ ((fr & 7) << 3))];
            // ---- PV: o = mfma(A=V^T rows=d, B=P cols=q) ----
            __builtin_amdgcn_s_setprio(1);
#pragma unroll
            for (int dt = 0; dt < 8; dt++) {
                const int vrow = dt * 16 + fr;
#pragma unroll
                for (int hh = 0; hh < 2; hh++) {
                    bf16x8 vb = *(const bf16x8*)&Vs[cur][vrow * 64 + (((hh * 4 + g) ^ (vrow & 7)) * 8)];
                    o[dt] = __builtin_amdgcn_mfma_f32_16x16x32_bf16(vb, pa[hh], o[dt], 0, 0, 0);
                }
            }
            __builtin_amdgcn_s_setprio(0);
        }
        __syncthreads();
        cur ^= 1;
    }
    flush();
}

extern "C" void kernel_launch(void* const* d_in, const int* in_sizes, int n_in,
                              void* d_out, int out_size, void* d_ws, size_t ws_size,
                              hipStream_t stream) {
    const float* hs = (const float*)d_in[0];
    const float* Wq = (const float*)d_in[1];
    const float* Wk = (const float*)d_in[2];
    const float* Wv = (const float*)d_in[3];
    const float* Wo = (const float*)d_in[4];
    float* out = (float*)d_out;

    size_t off = 0;
    char* wsb = (char*)d_ws;
    auto carve = [&](size_t bytes) { void* p = wsb + off; off += bytes; return p; };

    ushort_t* Xb   = (ushort_t*)carve((size_t)M_ROWS * DMODEL * 2);
    ushort_t* Wqb  = (ushort_t*)carve((size_t)DMODEL * DMODEL * 2); // Wq|Wk|Wv contiguous
    ushort_t* Wkb  = (ushort_t*)carve((size_t)DMODEL * DMODEL * 2);
    ushort_t* Wvb  = (ushort_t*)carve((size_t)DMODEL * DMODEL * 2);
    ushort_t* Wob  = (ushort_t*)carve((size_t)DMODEL * DMODEL * 2);
    ushort_t* Qb   = (ushort_t*)carve((size_t)BATCH * NH * S_LEN * HDIM * 2);
    ushort_t* Kb   = (ushort_t*)carve((size_t)BATCH * NH * S_LEN * HDIM * 2);
    ushort_t* Vtb  = (ushort_t*)carve((size_t)BATCH * NH * S_LEN * HDIM * 2);
    ushort_t* ctxb = (ushort_t*)carve((size_t)M_ROWS * DMODEL * 2);
    float* cosT    = (float*)carve((size_t)S_LEN * 64 * 4);
    float* sinT    = (float*)carve((size_t)S_LEN * 64 * 4);

    const int nX = M_ROWS * DMODEL;   // 8388608
    const int nW = DMODEL * DMODEL;   // 4194304

    cvt_bf16<<<(nX / 4) / 256, 256, 0, stream>>>(hs, Xb, nX / 4);
    cvt_bf16<<<(nW / 4) / 256, 256, 0, stream>>>(Wq, Wqb, nW / 4);
    cvt_bf16<<<(nW / 4) / 256, 256, 0, stream>>>(Wk, Wkb, nW / 4);
    cvt_bf16<<<(nW / 4) / 256, 256, 0, stream>>>(Wv, Wvb, nW / 4);
    cvt_bf16<<<(nW / 4) / 256, 256, 0, stream>>>(Wo, Wob, nW / 4);
    rope_tables<<<(S_LEN * 64) / 256, 256, 0, stream>>>(cosT, sinT);

    // Fused QKV projection: A = Xb [4096][2048], B = Wqb..Wvb as [6144][2048].
    gemm8<0><<<(M_ROWS / 128) * (3 * DMODEL / 256), 512, 0, stream>>>(
        Xb, Wqb, Qb, Kb, Vtb, 3 * DMODEL / 256, DMODEL);

    rope_inplace<<<(BATCH * NH * S_LEN * 64) / 256, 256, 0, stream>>>(Qb, Kb, cosT, sinT);

    attn_fwd_v4<<<512, 256, 0, stream>>>(Qb, Kb, Vtb, ctxb);

    // Output projection: fp32 result straight to d_out.
    gemm8<2><<<(M_ROWS / 128) * (DMODEL / 256), 512, 0, stream>>>(
        ctxb, Wob, out, nullptr, nullptr, DMODEL / 256, DMODEL);
}

// Round 7
// 283.879 us; speedup vs baseline: 2.2460x; 1.0381x over previous
//
#include <hip/hip_runtime.h>

typedef unsigned short ushort_t;
typedef __bf16 bf16x8 __attribute__((ext_vector_type(8)));
typedef float f32x4 __attribute__((ext_vector_type(4)));

#define S_LEN 2048
#define DMODEL 2048
#define NH 16
#define HDIM 128
#define BATCH 2
#define M_ROWS (BATCH * S_LEN) // 4096

__device__ __forceinline__ ushort_t f2bf(float f) {
    union { float f; unsigned u; } v; v.f = f;
    unsigned r = (v.u + 0x7fffu + ((v.u >> 16) & 1u)) >> 16;
    return (ushort_t)r;
}
__device__ __forceinline__ float bf2f(ushort_t u) {
    union { unsigned u; float f; } v; v.u = ((unsigned)u) << 16;
    return v.f;
}

__device__ __forceinline__ void async16(const void* g, void* l) {
    __builtin_amdgcn_global_load_lds(
        (const __attribute__((address_space(1))) void*)g,
        (__attribute__((address_space(3))) void*)l, 16, 0, 0);
}

// ---------------- fp32 -> bf16 (4 elems/thread) ----------------
__global__ void cvt_bf16(const float* __restrict__ in, ushort_t* __restrict__ out, int n4) {
    int i = blockIdx.x * blockDim.x + threadIdx.x;
    if (i >= n4) return;
    float4 f = ((const float4*)in)[i];
    ushort4 u;
    u.x = f2bf(f.x); u.y = f2bf(f.y); u.z = f2bf(f.z); u.w = f2bf(f.w);
    ((ushort4*)out)[i] = u;
}

// ---------------- fp32 -> bf16 for the 4 weight matrices in one launch ----------
__global__ void cvt4_bf16(const float* __restrict__ w0, const float* __restrict__ w1,
                          const float* __restrict__ w2, const float* __restrict__ w3,
                          ushort_t* __restrict__ out, int n4) {
    int i = blockIdx.x * blockDim.x + threadIdx.x;
    if (i >= n4) return;
    int which = blockIdx.y;
    const float* src = which == 0 ? w0 : which == 1 ? w1 : which == 2 ? w2 : w3;
    float4 f = ((const float4*)src)[i];
    ushort4 u;
    u.x = f2bf(f.x); u.y = f2bf(f.y); u.z = f2bf(f.z); u.w = f2bf(f.w);
    ((ushort4*)(out + (size_t)which * DMODEL * DMODEL))[i] = u;
}

// ---------------- RoPE tables [S][64] ----------------
__global__ void rope_tables(float* __restrict__ cosT, float* __restrict__ sinT) {
    int i = blockIdx.x * blockDim.x + threadIdx.x; // 2048*64
    int s = i >> 6, f = i & 63;
    float inv = powf(10000.0f, -(float)(2 * f) / 128.0f);
    float ang = (float)s * inv;
    cosT[i] = cosf(ang);
    sinT[i] = sinf(ang);
}

// ---------------- RoPE in-place on Q and K ([BH][S][HD] bf16) ----------------
__global__ void rope_inplace(ushort_t* __restrict__ Q, ushort_t* __restrict__ K,
                             const float* __restrict__ cosT, const float* __restrict__ sinT) {
    long i = (long)blockIdx.x * blockDim.x + threadIdx.x; // 32*2048*64
    int f = (int)(i & 63);
    long t = i >> 6;
    int s = (int)(t & (S_LEN - 1));
    int bh = (int)(t >> 11);
    long base = ((long)bh * S_LEN + s) * HDIM;
    float c = cosT[s * 64 + f], sn = sinT[s * 64 + f];
    float a0 = bf2f(Q[base + f]), a1 = bf2f(Q[base + 64 + f]);
    Q[base + f]      = f2bf(a0 * c - a1 * sn);
    Q[base + 64 + f] = f2bf(a1 * c + a0 * sn);
    float b0 = bf2f(K[base + f]), b1 = bf2f(K[base + 64 + f]);
    K[base + f]      = f2bf(b0 * c - b1 * sn);
    K[base + 64 + f] = f2bf(b1 * c + b0 * sn);
}

// ================= gemm256: BM=256, BN=NF*64, BK=64, 512 threads (8 waves 2x4) ======
// Per-wave output 128 x (NF*16... actually NF n-frags of 16): WM=128, WN=NF*16*... 
// wn selects a 48/64-col slice; per-wave tile 128 x (NF*16). Fragment-bytes/FLOP low
// enough to be MFMA-bound (not LDS-read-bound). 3-bit XOR swizzle (conflict-free,
// verified R6), per-XCD B-column-slice decode, counted-vmcnt 2-deep pipeline.
// EPI 0: cols indexed over fused [Q|K|V] (N=6144), per-frag proj decode; V transposed.
// EPI 2: fp32 row-major to d_out.
template <int EPI, int NF>
__global__ __launch_bounds__(512) void gemm256(
    const ushort_t* __restrict__ A, const ushort_t* __restrict__ Bm,
    void* __restrict__ C0, void* __restrict__ C1, void* __restrict__ C2,
    int NB, int K) {
    __shared__ __align__(16) ushort_t As[2][256 * 64];
    __shared__ __align__(16) ushort_t Bs[2][NF * 64 * 64];
    const int tid = threadIdx.x;
    const int lane = tid & 63;
    const int w = tid >> 6;
    const int wm = w >> 2, wn = w & 3;     // 2 x 4 waves
    const int fr = lane & 15, g = lane >> 4;
    const int WN = NF * 16;
    const int BN = NF * 64;
    // XCD c owns B col-blocks [c*cpx, (c+1)*cpx)
    const int cpx = NB >> 3;
    const int xcd = blockIdx.x & 7;
    const int local = blockIdx.x >> 3;
    const int brow = (local / cpx) * 256;
    const int bcol = (xcd * cpx + local % cpx) * BN;

    // staging: linear LDS dest, involutive pre-swizzled global source
    int aRow[4], aK[4], bRow[NF], bK[NF];
#pragma unroll
    for (int q = 0; q < 4; q++) {
        int d = (q * 512 + tid) * 16;
        int row = d >> 7;
        int s = d ^ ((row & 7) << 4);
        aRow[q] = row; aK[q] = (s & 127) >> 1;
    }
#pragma unroll
    for (int q = 0; q < NF; q++) {
        int d = (q * 512 + tid) * 16;
        int row = d >> 7;
        int s = d ^ ((row & 7) << 4);
        bRow[q] = row; bK[q] = (s & 127) >> 1;
    }

    f32x4 acc[8][NF];
#pragma unroll
    for (int m = 0; m < 8; m++)
#pragma unroll
        for (int n = 0; n < NF; n++) acc[m][n] = (f32x4){0.f, 0.f, 0.f, 0.f};

    auto stage = [&](int buf, int k0) {
#pragma unroll
        for (int q = 0; q < 4; q++)
            async16(&A[(long)(brow + aRow[q]) * K + k0 + aK[q]], &As[buf][(q * 512 + tid) * 8]);
#pragma unroll
        for (int q = 0; q < NF; q++)
            async16(&Bm[(long)(bcol + bRow[q]) * K + k0 + bK[q]], &Bs[buf][(q * 512 + tid) * 8]);
    };
    auto rdA = [&](int buf, int m, int ks) -> bf16x8 {
        int row = wm * 128 + m * 16 + fr;
        int cb = (ks * 64 + g * 16) ^ ((row & 7) << 4);
        return *(const bf16x8*)((const char*)&As[buf][0] + row * 128 + cb);
    };
    auto rdB = [&](int buf, int n, int ks) -> bf16x8 {
        int row = wn * WN + n * 16 + fr;
        int cb = (ks * 64 + g * 16) ^ ((row & 7) << 4);
        return *(const bf16x8*)((const char*)&Bs[buf][0] + row * 128 + cb);
    };

    const int NT = K / 64;
    stage(0, 0);
    stage(1, 64);

    for (int kt = 0; kt < NT; ++kt) {
        const int cur = kt & 1;
        if (kt + 1 < NT) {
            if constexpr (NF == 3) asm volatile("s_waitcnt vmcnt(7)" ::: "memory");
            else                   asm volatile("s_waitcnt vmcnt(8)" ::: "memory");
        } else {
            asm volatile("s_waitcnt vmcnt(0)" ::: "memory");
        }
        __builtin_amdgcn_sched_barrier(0);
        __builtin_amdgcn_s_barrier();
        __builtin_amdgcn_sched_barrier(0);

        bf16x8 af[8][2], bf[NF][2];
        // ---- ph0: a m0-3 + b n0-1; MFMA m0-3 x n0-1 ----
#pragma unroll
        for (int m = 0; m < 4; m++)
#pragma unroll
            for (int ks = 0; ks < 2; ks++) af[m][ks] = rdA(cur, m, ks);
#pragma unroll
        for (int n = 0; n < 2; n++)
#pragma unroll
            for (int ks = 0; ks < 2; ks++) bf[n][ks] = rdB(cur, n, ks);
        __builtin_amdgcn_s_setprio(1);
#pragma unroll
        for (int m = 0; m < 4; m++)
#pragma unroll
            for (int n = 0; n < 2; n++)
#pragma unroll
                for (int ks = 0; ks < 2; ks++)
                    acc[m][n] = __builtin_amdgcn_mfma_f32_16x16x32_bf16(af[m][ks], bf[n][ks], acc[m][n], 0, 0, 0);
        __builtin_amdgcn_s_setprio(0);
        // ---- ph1: a m4-7; MFMA m4-7 x n0-1 ----
#pragma unroll
        for (int m = 4; m < 8; m++)
#pragma unroll
            for (int ks = 0; ks < 2; ks++) af[m][ks] = rdA(cur, m, ks);
        __builtin_amdgcn_s_setprio(1);
#pragma unroll
        for (int m = 4; m < 8; m++)
#pragma unroll
            for (int n = 0; n < 2; n++)
#pragma unroll
                for (int ks = 0; ks < 2; ks++)
                    acc[m][n] = __builtin_amdgcn_mfma_f32_16x16x32_bf16(af[m][ks], bf[n][ks], acc[m][n], 0, 0, 0);
        __builtin_amdgcn_s_setprio(0);
        // ---- ph2: b n2..NF-1; MFMA m0-7 x n2..NF-1 ----
#pragma unroll
        for (int n = 2; n < NF; n++)
#pragma unroll
            for (int ks = 0; ks < 2; ks++) bf[n][ks] = rdB(cur, n, ks);
        __builtin_amdgcn_s_setprio(1);
#pragma unroll
        for (int m = 0; m < 8; m++)
#pragma unroll
            for (int n = 2; n < NF; n++)
#pragma unroll
                for (int ks = 0; ks < 2; ks++)
                    acc[m][n] = __builtin_amdgcn_mfma_f32_16x16x32_bf16(af[m][ks], bf[n][ks], acc[m][n], 0, 0, 0);
        __builtin_amdgcn_s_setprio(0);

        __builtin_amdgcn_s_barrier();   // all waves done reading buf cur
        __builtin_amdgcn_sched_barrier(0);
        if (kt + 2 < NT) stage(cur, (kt + 2) * 64);
    }

    const int rbase = brow + wm * 128;
    if constexpr (EPI == 0) {
#pragma unroll
        for (int n = 0; n < NF; n++) {
            int c2abs = bcol + wn * WN + n * 16 + fr;   // [0, 6144)
            int proj = c2abs >> 11;                     // frag never straddles (16 | 2048)
            int c2 = c2abs & 2047;
            int h = c2 >> 7, hd = c2 & 127;
            if (proj < 2) {
                ushort_t* dst = (ushort_t*)(proj == 0 ? C0 : C1);
#pragma unroll
                for (int m = 0; m < 8; m++)
#pragma unroll
                    for (int r = 0; r < 4; r++) {
                        int row = rbase + m * 16 + g * 4 + r;
                        int b = row >> 11, s = row & (S_LEN - 1);
                        dst[(((long)(b * NH + h) * S_LEN) + s) * HDIM + hd] = f2bf(acc[m][n][r]);
                    }
            } else {
                ushort_t* dst = (ushort_t*)C2;
#pragma unroll
                for (int m = 0; m < 8; m++) {
                    int row0 = rbase + m * 16 + g * 4;
                    int b = row0 >> 11, s0 = row0 & (S_LEN - 1);
                    ushort4 u;
                    u.x = f2bf(acc[m][n][0]); u.y = f2bf(acc[m][n][1]);
                    u.z = f2bf(acc[m][n][2]); u.w = f2bf(acc[m][n][3]);
                    *(ushort4*)&dst[(((long)(b * NH + h) * HDIM) + hd) * S_LEN + s0] = u;
                }
            }
        }
    } else {
        float* dst = (float*)C0;
#pragma unroll
        for (int m = 0; m < 8; m++)
#pragma unroll
            for (int n = 0; n < NF; n++) {
                int col = bcol + wn * WN + n * 16 + fr;
#pragma unroll
                for (int r = 0; r < 4; r++) {
                    int row = rbase + m * 16 + g * 4 + r;
                    dst[(long)row * DMODEL + col] = acc[m][n][r];
                }
            }
    }
}

// ---------------- Flash attention v4: uniform work pairing ----------
__global__ __launch_bounds__(256) void attn_fwd_v4(
    const ushort_t* __restrict__ Q, const ushort_t* __restrict__ K,
    const ushort_t* __restrict__ Vt, ushort_t* __restrict__ ctx) {
    __shared__ __align__(16) ushort_t Ks[2][64 * 128];
    __shared__ __align__(16) ushort_t Vs[2][128 * 64];
    __shared__ __align__(16) ushort_t Pls[4][16 * 64];

    const int tid = threadIdx.x;
    const int lane = tid & 63;
    const int w = tid >> 6;
    const int g = lane >> 4;
    const int fr = lane & 15;
    const int fk = g * 8;

    const int bid = blockIdx.x;              // 512 blocks
    const int xcd = bid & 7;
    const int t6 = bid >> 3;                 // 0..63
    const int bh = xcd + 8 * (t6 & 3);       // 4 heads per XCD
    const int p = t6 >> 2;                   // 0..15 pair index
    const int qtA = p, qtB = 31 - p;
    const int b = bh >> 4, h = bh & 15;

    const ushort_t* Qb = Q + (long)bh * S_LEN * HDIM;
    const ushort_t* Kb = K + (long)bh * S_LEN * HDIM;
    const ushort_t* Vb = Vt + (long)bh * HDIM * S_LEN;

    int koff[4], voff[4], kdst[4], vdst[4];
#pragma unroll
    for (int r = 0; r < 4; r++) {
        int ci = r * 256 + tid;
        int krow = ci >> 4, kwc = ci & 15;
        koff[r] = krow * HDIM + ((kwc ^ (krow & 7)) * 8);
        kdst[r] = ci * 8;
        int vrow = ci >> 3, vwc = ci & 7;
        voff[r] = vrow * S_LEN + ((vwc ^ (vrow & 7)) * 8);
        vdst[r] = ci * 8;
    }
    auto stage = [&](int buf, int kv0) {
        const ushort_t* Kg = Kb + (long)kv0 * HDIM;
        const ushort_t* Vg = Vb + kv0;
#pragma unroll
        for (int r = 0; r < 4; r++) async16(Kg + koff[r], &Ks[buf][kdst[r]]);
#pragma unroll
        for (int r = 0; r < 4; r++) async16(Vg + voff[r], &Vs[buf][vdst[r]]);
    };

    int qrow0 = qtA * 64 + w * 16;
    bf16x8 qf[4];
    auto loadQ = [&]() {
#pragma unroll
        for (int t = 0; t < 4; t++)
            qf[t] = *(const bf16x8*)&Qb[(long)(qrow0 + fr) * HDIM + t * 32 + fk];
    };
    loadQ();

    f32x4 o[8];
#pragma unroll
    for (int i = 0; i < 8; i++) o[i] = (f32x4){0.f, 0.f, 0.f, 0.f};
    float mrun = -1e30f, lrun = 0.f;

    const float scale = 0.08838834764831845f; // 1/sqrt(128)
    long obase = ((long)b * S_LEN) * DMODEL + (long)h * HDIM;
    auto flush = [&]() {
        float inv = 1.0f / lrun;
        long rowb = obase + (long)(qrow0 + fr) * DMODEL;
#pragma unroll
        for (int dt = 0; dt < 8; dt++) {
            ushort4 u;
            u.x = f2bf(o[dt][0] * inv); u.y = f2bf(o[dt][1] * inv);
            u.z = f2bf(o[dt][2] * inv); u.w = f2bf(o[dt][3] * inv);
            *(ushort4*)&ctx[rowb + dt * 16 + g * 4] = u;
        }
    };

    const int ntA = qtA + 1;
    const int ntot = 33; // ntA + (qtB+1) = 33 for every block

    stage(0, 0);
    __syncthreads();

    int cur = 0;
    for (int u = 0; u < ntot; ++u) {
        if (u + 1 < ntot) {
            int kvn = (u + 1 < ntA) ? (u + 1) : (u + 1 - ntA);
            stage(cur ^ 1, kvn * 64);
        }
        const int kv0 = ((u < ntA) ? u : (u - ntA)) * 64;
        if (u == ntA) { // phase switch A -> B
            flush();
            qrow0 = qtB * 64 + w * 16;
            loadQ();
#pragma unroll
            for (int i = 0; i < 8; i++) o[i] = (f32x4){0.f, 0.f, 0.f, 0.f};
            mrun = -1e30f; lrun = 0.f;
        }
        if (kv0 <= qrow0 + 15) {
            // ---- QK^T (swapped: A=K rows=kv, B=Q cols=q) ----
            f32x4 sf[4]; // [c]: kv = kv0+c*16+g*4+r, q = qrow0+fr
#pragma unroll
            for (int c = 0; c < 4; c++) sf[c] = (f32x4){0.f, 0.f, 0.f, 0.f};
            __builtin_amdgcn_s_setprio(1);
#pragma unroll
            for (int c = 0; c < 4; c++) {
                const int krow = c * 16 + fr;
#pragma unroll
                for (int tt = 0; tt < 4; tt++) {
                    bf16x8 kb = *(const bf16x8*)&Ks[cur][krow * 128 + (((tt * 4 + g) ^ (krow & 7)) * 8)];
                    sf[c] = __builtin_amdgcn_mfma_f32_16x16x32_bf16(kb, qf[tt], sf[c], 0, 0, 0);
                }
            }
            __builtin_amdgcn_s_setprio(0);
            // ---- scale + causal mask ----
            if (kv0 + 63 <= qrow0) {
#pragma unroll
                for (int c = 0; c < 4; c++)
#pragma unroll
                    for (int r = 0; r < 4; r++) sf[c][r] *= scale;
            } else {
                const int q = qrow0 + fr;
#pragma unroll
                for (int c = 0; c < 4; c++)
#pragma unroll
                    for (int r = 0; r < 4; r++) {
                        int kv = kv0 + c * 16 + g * 4 + r;
                        sf[c][r] = (kv <= q) ? sf[c][r] * scale : -1e30f;
                    }
            }
            // ---- online softmax (lane owns 16 kv of its q-row) ----
            {
                float vmax = -1e30f;
#pragma unroll
                for (int c = 0; c < 4; c++) {
                    float t0 = fmaxf(fmaxf(sf[c][0], sf[c][1]), fmaxf(sf[c][2], sf[c][3]));
                    vmax = fmaxf(vmax, t0);
                }
                vmax = fmaxf(vmax, __shfl_xor(vmax, 16));
                vmax = fmaxf(vmax, __shfl_xor(vmax, 32));
                if (!__all(vmax - mrun <= 8.f)) { // defer-max
                    float nm = fmaxf(mrun, vmax);
                    float alpha = __expf(mrun - nm);
                    mrun = nm;
                    lrun *= alpha;
#pragma unroll
                    for (int dt = 0; dt < 8; dt++) o[dt] *= alpha;
                }
                float rs = 0.f;
#pragma unroll
                for (int c = 0; c < 4; c++)
#pragma unroll
                    for (int r = 0; r < 4; r++) {
                        float pv = __expf(sf[c][r] - mrun);
                        sf[c][r] = pv;
                        rs += pv;
                    }
                rs += __shfl_xor(rs, 16);
                rs += __shfl_xor(rs, 32);
                lrun += rs;
            }
            // ---- P -> LDS [q=16][kv=64], b64-packed, XOR-swizzled ----
#pragma unroll
            for (int c = 0; c < 4; c++) {
                ushort4 u;
                u.x = f2bf(sf[c][0]); u.y = f2bf(sf[c][1]);
                u.z = f2bf(sf[c][2]); u.w = f2bf(sf[c][3]);
                *(ushort4*)&Pls[w][fr * 64 + ((c * 16 + g * 4) ^ ((fr & 7) << 3))] = u;
            }
            bf16x8 pa[2]; // B-frag: P[kv=hh*32+g*8+j][q=fr]
#pragma unroll
            for (int hh = 0; hh < 2; hh++)
                pa[hh] = *(const bf16x8*)&Pls[w][fr * 64 + ((hh * 32 + g * 8) ^ ((fr & 7) << 3))];
            // ---- PV: o = mfma(A=V^T rows=d, B=P cols=q) ----
            __builtin_amdgcn_s_setprio(1);
#pragma unroll
            for (int dt = 0; dt < 8; dt++) {
                const int vrow = dt * 16 + fr;
#pragma unroll
                for (int hh = 0; hh < 2; hh++) {
                    bf16x8 vb = *(const bf16x8*)&Vs[cur][vrow * 64 + (((hh * 4 + g) ^ (vrow & 7)) * 8)];
                    o[dt] = __builtin_amdgcn_mfma_f32_16x16x32_bf16(vb, pa[hh], o[dt], 0, 0, 0);
                }
            }
            __builtin_amdgcn_s_setprio(0);
        }
        __syncthreads();
        cur ^= 1;
    }
    flush();
}

extern "C" void kernel_launch(void* const* d_in, const int* in_sizes, int n_in,
                              void* d_out, int out_size, void* d_ws, size_t ws_size,
                              hipStream_t stream) {
    const float* hs = (const float*)d_in[0];
    const float* Wq = (const float*)d_in[1];
    const float* Wk = (const float*)d_in[2];
    const float* Wv = (const float*)d_in[3];
    const float* Wo = (const float*)d_in[4];
    float* out = (float*)d_out;

    size_t off = 0;
    char* wsb = (char*)d_ws;
    auto carve = [&](size_t bytes) { void* p = wsb + off; off += bytes; return p; };

    ushort_t* Xb   = (ushort_t*)carve((size_t)M_ROWS * DMODEL * 2);
    ushort_t* Wqb  = (ushort_t*)carve((size_t)DMODEL * DMODEL * 2); // Wq|Wk|Wv|Wo contiguous
    ushort_t* Wkb  = (ushort_t*)carve((size_t)DMODEL * DMODEL * 2);
    ushort_t* Wvb  = (ushort_t*)carve((size_t)DMODEL * DMODEL * 2);
    ushort_t* Wob  = (ushort_t*)carve((size_t)DMODEL * DMODEL * 2);
    ushort_t* Qb   = (ushort_t*)carve((size_t)BATCH * NH * S_LEN * HDIM * 2);
    ushort_t* Kb   = (ushort_t*)carve((size_t)BATCH * NH * S_LEN * HDIM * 2);
    ushort_t* Vtb  = (ushort_t*)carve((size_t)BATCH * NH * S_LEN * HDIM * 2);
    ushort_t* ctxb = (ushort_t*)carve((size_t)M_ROWS * DMODEL * 2);
    float* cosT    = (float*)carve((size_t)S_LEN * 64 * 4);
    float* sinT    = (float*)carve((size_t)S_LEN * 64 * 4);

    const int nX = M_ROWS * DMODEL;   // 8388608
    const int nW = DMODEL * DMODEL;   // 4194304

    cvt_bf16<<<(nX / 4) / 256, 256, 0, stream>>>(hs, Xb, nX / 4);
    cvt4_bf16<<<dim3((nW / 4) / 256, 4), 256, 0, stream>>>(Wq, Wk, Wv, Wo, Wqb, nW / 4);
    rope_tables<<<(S_LEN * 64) / 256, 256, 0, stream>>>(cosT, sinT);

    // Fused QKV projection: A = Xb [4096][2048], B = Wqb..Wvb as [6144][2048].
    // BM=256, BN=192 -> grid 16 x 32 = 512 blocks = exactly 2 rounds on 256 CUs.
    gemm256<0, 3><<<(M_ROWS / 256) * (3 * DMODEL / 192), 512, 0, stream>>>(
        Xb, Wqb, Qb, Kb, Vtb, 3 * DMODEL / 192, DMODEL);

    rope_inplace<<<(BATCH * NH * S_LEN * 64) / 256, 256, 0, stream>>>(Qb, Kb, cosT, sinT);

    attn_fwd_v4<<<512, 256, 0, stream>>>(Qb, Kb, Vtb, ctxb);

    // Output projection: BM=256, BN=256 -> grid 16 x 8 = 128 blocks, fp32 to d_out.
    gemm256<2, 4><<<(M_ROWS / 256) * (DMODEL / 256), 512, 0, stream>>>(
        ctxb, Wob, out, nullptr, nullptr, DMODEL / 256, DMODEL);
}

// Round 8
// 263.732 us; speedup vs baseline: 2.4176x; 1.0764x over previous
//
#include <hip/hip_runtime.h>

typedef unsigned short ushort_t;
typedef __bf16 bf16x8 __attribute__((ext_vector_type(8)));
typedef float f32x4 __attribute__((ext_vector_type(4)));

#define S_LEN 2048
#define DMODEL 2048
#define NH 16
#define HDIM 128
#define BATCH 2
#define M_ROWS (BATCH * S_LEN) // 4096

__device__ __forceinline__ ushort_t f2bf(float f) {
    union { float f; unsigned u; } v; v.f = f;
    unsigned r = (v.u + 0x7fffu + ((v.u >> 16) & 1u)) >> 16;
    return (ushort_t)r;
}
__device__ __forceinline__ float bf2f(ushort_t u) {
    union { unsigned u; float f; } v; v.u = ((unsigned)u) << 16;
    return v.f;
}

__device__ __forceinline__ void async16(const void* g, void* l) {
    __builtin_amdgcn_global_load_lds(
        (const __attribute__((address_space(1))) void*)g,
        (__attribute__((address_space(3))) void*)l, 16, 0, 0);
}

// ---------------- fp32 -> bf16 (4 elems/thread) ----------------
__global__ void cvt_bf16(const float* __restrict__ in, ushort_t* __restrict__ out, int n4) {
    int i = blockIdx.x * blockDim.x + threadIdx.x;
    if (i >= n4) return;
    float4 f = ((const float4*)in)[i];
    ushort4 u;
    u.x = f2bf(f.x); u.y = f2bf(f.y); u.z = f2bf(f.z); u.w = f2bf(f.w);
    ((ushort4*)out)[i] = u;
}

// ---------------- fp32 -> bf16 for the 4 weight matrices in one launch ----------
__global__ void cvt4_bf16(const float* __restrict__ w0, const float* __restrict__ w1,
                          const float* __restrict__ w2, const float* __restrict__ w3,
                          ushort_t* __restrict__ out, int n4) {
    int i = blockIdx.x * blockDim.x + threadIdx.x;
    if (i >= n4) return;
    int which = blockIdx.y;
    const float* src = which == 0 ? w0 : which == 1 ? w1 : which == 2 ? w2 : w3;
    float4 f = ((const float4*)src)[i];
    ushort4 u;
    u.x = f2bf(f.x); u.y = f2bf(f.y); u.z = f2bf(f.z); u.w = f2bf(f.w);
    ((ushort4*)(out + (size_t)which * DMODEL * DMODEL))[i] = u;
}

// ---------------- RoPE tables [S][64] ----------------
__global__ void rope_tables(float* __restrict__ cosT, float* __restrict__ sinT) {
    int i = blockIdx.x * blockDim.x + threadIdx.x; // 2048*64
    int s = i >> 6, f = i & 63;
    float inv = powf(10000.0f, -(float)(2 * f) / 128.0f);
    float ang = (float)s * inv;
    cosT[i] = cosf(ang);
    sinT[i] = sinf(ang);
}

// ---------------- RoPE in-place on Q and K ([BH][S][HD] bf16) ----------------
__global__ void rope_inplace(ushort_t* __restrict__ Q, ushort_t* __restrict__ K,
                             const float* __restrict__ cosT, const float* __restrict__ sinT) {
    long i = (long)blockIdx.x * blockDim.x + threadIdx.x; // 32*2048*64
    int f = (int)(i & 63);
    long t = i >> 6;
    int s = (int)(t & (S_LEN - 1));
    int bh = (int)(t >> 11);
    long base = ((long)bh * S_LEN + s) * HDIM;
    float c = cosT[s * 64 + f], sn = sinT[s * 64 + f];
    float a0 = bf2f(Q[base + f]), a1 = bf2f(Q[base + 64 + f]);
    Q[base + f]      = f2bf(a0 * c - a1 * sn);
    Q[base + 64 + f] = f2bf(a1 * c + a0 * sn);
    float b0 = bf2f(K[base + f]), b1 = bf2f(K[base + 64 + f]);
    K[base + f]      = f2bf(b0 * c - b1 * sn);
    K[base + 64 + f] = f2bf(b1 * c + b0 * sn);
}

// ================= gemm256: BM=256, BN=NF*64, BK=64, 512 threads (8 waves 2x4) ======
// Schedule per K-tile: counted-vmcnt wait + barrier; issue ALL fragment ds_reads
// up front (B first, then A m0..m7) in ONE scheduling region; single setprio(1)
// MFMA block m-major -> compiler emits rolling counted lgkmcnt so the A-read tail
// overlaps the head MFMAs. No interior scheduler fences (R7 fix: per-phase setprio
// fences serialized reads vs MFMA at 2 waves/SIMD).
template <int EPI, int NF>
__global__ __launch_bounds__(512) void gemm256(
    const ushort_t* __restrict__ A, const ushort_t* __restrict__ Bm,
    void* __restrict__ C0, void* __restrict__ C1, void* __restrict__ C2,
    int NB, int K) {
    __shared__ __align__(16) ushort_t As[2][256 * 64];
    __shared__ __align__(16) ushort_t Bs[2][NF * 64 * 64];
    const int tid = threadIdx.x;
    const int lane = tid & 63;
    const int w = tid >> 6;
    const int wm = w >> 2, wn = w & 3;     // 2 x 4 waves
    const int fr = lane & 15, g = lane >> 4;
    const int WN = NF * 16;
    const int BN = NF * 64;
    // XCD c owns B col-blocks [c*cpx, (c+1)*cpx)
    const int cpx = NB >> 3;
    const int xcd = blockIdx.x & 7;
    const int local = blockIdx.x >> 3;
    const int brow = (local / cpx) * 256;
    const int bcol = (xcd * cpx + local % cpx) * BN;

    // staging: linear LDS dest, involutive pre-swizzled global source
    int aRow[4], aK[4], bRow[NF], bK[NF];
#pragma unroll
    for (int q = 0; q < 4; q++) {
        int d = (q * 512 + tid) * 16;
        int row = d >> 7;
        int s = d ^ ((row & 7) << 4);
        aRow[q] = row; aK[q] = (s & 127) >> 1;
    }
#pragma unroll
    for (int q = 0; q < NF; q++) {
        int d = (q * 512 + tid) * 16;
        int row = d >> 7;
        int s = d ^ ((row & 7) << 4);
        bRow[q] = row; bK[q] = (s & 127) >> 1;
    }

    f32x4 acc[8][NF];
#pragma unroll
    for (int m = 0; m < 8; m++)
#pragma unroll
        for (int n = 0; n < NF; n++) acc[m][n] = (f32x4){0.f, 0.f, 0.f, 0.f};

    auto stage = [&](int buf, int k0) {
#pragma unroll
        for (int q = 0; q < 4; q++)
            async16(&A[(long)(brow + aRow[q]) * K + k0 + aK[q]], &As[buf][(q * 512 + tid) * 8]);
#pragma unroll
        for (int q = 0; q < NF; q++)
            async16(&Bm[(long)(bcol + bRow[q]) * K + k0 + bK[q]], &Bs[buf][(q * 512 + tid) * 8]);
    };
    auto rdA = [&](int buf, int m, int ks) -> bf16x8 {
        int row = wm * 128 + m * 16 + fr;
        int cb = (ks * 64 + g * 16) ^ ((row & 7) << 4);
        return *(const bf16x8*)((const char*)&As[buf][0] + row * 128 + cb);
    };
    auto rdB = [&](int buf, int n, int ks) -> bf16x8 {
        int row = wn * WN + n * 16 + fr;
        int cb = (ks * 64 + g * 16) ^ ((row & 7) << 4);
        return *(const bf16x8*)((const char*)&Bs[buf][0] + row * 128 + cb);
    };

    const int NT = K / 64;
    stage(0, 0);
    stage(1, 64);

    for (int kt = 0; kt < NT; ++kt) {
        const int cur = kt & 1;
        if (kt + 1 < NT) {
            if constexpr (NF == 2)      asm volatile("s_waitcnt vmcnt(6)" ::: "memory");
            else if constexpr (NF == 3) asm volatile("s_waitcnt vmcnt(7)" ::: "memory");
            else                        asm volatile("s_waitcnt vmcnt(8)" ::: "memory");
        } else {
            asm volatile("s_waitcnt vmcnt(0)" ::: "memory");
        }
        __builtin_amdgcn_sched_barrier(0);
        __builtin_amdgcn_s_barrier();
        __builtin_amdgcn_sched_barrier(0);

        // ---- issue ALL fragment reads: B first, then A in consumption order ----
        bf16x8 bfv[NF][2], af[8][2];
#pragma unroll
        for (int n = 0; n < NF; n++)
#pragma unroll
            for (int ks = 0; ks < 2; ks++) bfv[n][ks] = rdB(cur, n, ks);
#pragma unroll
        for (int m = 0; m < 8; m++)
#pragma unroll
            for (int ks = 0; ks < 2; ks++) af[m][ks] = rdA(cur, m, ks);
        // ---- single MFMA block, m-major (af[m] retires just in time) ----
        __builtin_amdgcn_s_setprio(1);
#pragma unroll
        for (int m = 0; m < 8; m++)
#pragma unroll
            for (int n = 0; n < NF; n++)
#pragma unroll
                for (int ks = 0; ks < 2; ks++)
                    acc[m][n] = __builtin_amdgcn_mfma_f32_16x16x32_bf16(af[m][ks], bfv[n][ks], acc[m][n], 0, 0, 0);
        __builtin_amdgcn_s_setprio(0);

        __builtin_amdgcn_s_barrier();   // all waves done reading buf cur
        __builtin_amdgcn_sched_barrier(0);
        if (kt + 2 < NT) stage(cur, (kt + 2) * 64);
    }

    const int rbase = brow + wm * 128;
    if constexpr (EPI == 0) {
#pragma unroll
        for (int n = 0; n < NF; n++) {
            int c2abs = bcol + wn * WN + n * 16 + fr;   // [0, 6144)
            int proj = c2abs >> 11;                     // frag never straddles (16 | 2048)
            int c2 = c2abs & 2047;
            int h = c2 >> 7, hd = c2 & 127;
            if (proj < 2) {
                ushort_t* dst = (ushort_t*)(proj == 0 ? C0 : C1);
#pragma unroll
                for (int m = 0; m < 8; m++)
#pragma unroll
                    for (int r = 0; r < 4; r++) {
                        int row = rbase + m * 16 + g * 4 + r;
                        int b = row >> 11, s = row & (S_LEN - 1);
                        dst[(((long)(b * NH + h) * S_LEN) + s) * HDIM + hd] = f2bf(acc[m][n][r]);
                    }
            } else {
                ushort_t* dst = (ushort_t*)C2;
#pragma unroll
                for (int m = 0; m < 8; m++) {
                    int row0 = rbase + m * 16 + g * 4;
                    int b = row0 >> 11, s0 = row0 & (S_LEN - 1);
                    ushort4 u;
                    u.x = f2bf(acc[m][n][0]); u.y = f2bf(acc[m][n][1]);
                    u.z = f2bf(acc[m][n][2]); u.w = f2bf(acc[m][n][3]);
                    *(ushort4*)&dst[(((long)(b * NH + h) * HDIM) + hd) * S_LEN + s0] = u;
                }
            }
        }
    } else {
        float* dst = (float*)C0;
#pragma unroll
        for (int m = 0; m < 8; m++)
#pragma unroll
            for (int n = 0; n < NF; n++) {
                int col = bcol + wn * WN + n * 16 + fr;
#pragma unroll
                for (int r = 0; r < 4; r++) {
                    int row = rbase + m * 16 + g * 4 + r;
                    dst[(long)row * DMODEL + col] = acc[m][n][r];
                }
            }
    }
}

// ---------------- Flash attention v4: uniform work pairing ----------
__global__ __launch_bounds__(256) void attn_fwd_v4(
    const ushort_t* __restrict__ Q, const ushort_t* __restrict__ K,
    const ushort_t* __restrict__ Vt, ushort_t* __restrict__ ctx) {
    __shared__ __align__(16) ushort_t Ks[2][64 * 128];
    __shared__ __align__(16) ushort_t Vs[2][128 * 64];
    __shared__ __align__(16) ushort_t Pls[4][16 * 64];

    const int tid = threadIdx.x;
    const int lane = tid & 63;
    const int w = tid >> 6;
    const int g = lane >> 4;
    const int fr = lane & 15;
    const int fk = g * 8;

    const int bid = blockIdx.x;              // 512 blocks
    const int xcd = bid & 7;
    const int t6 = bid >> 3;                 // 0..63
    const int bh = xcd + 8 * (t6 & 3);       // 4 heads per XCD
    const int p = t6 >> 2;                   // 0..15 pair index
    const int qtA = p, qtB = 31 - p;
    const int b = bh >> 4, h = bh & 15;

    const ushort_t* Qb = Q + (long)bh * S_LEN * HDIM;
    const ushort_t* Kb = K + (long)bh * S_LEN * HDIM;
    const ushort_t* Vb = Vt + (long)bh * HDIM * S_LEN;

    int koff[4], voff[4], kdst[4], vdst[4];
#pragma unroll
    for (int r = 0; r < 4; r++) {
        int ci = r * 256 + tid;
        int krow = ci >> 4, kwc = ci & 15;
        koff[r] = krow * HDIM + ((kwc ^ (krow & 7)) * 8);
        kdst[r] = ci * 8;
        int vrow = ci >> 3, vwc = ci & 7;
        voff[r] = vrow * S_LEN + ((vwc ^ (vrow & 7)) * 8);
        vdst[r] = ci * 8;
    }
    auto stage = [&](int buf, int kv0) {
        const ushort_t* Kg = Kb + (long)kv0 * HDIM;
        const ushort_t* Vg = Vb + kv0;
#pragma unroll
        for (int r = 0; r < 4; r++) async16(Kg + koff[r], &Ks[buf][kdst[r]]);
#pragma unroll
        for (int r = 0; r < 4; r++) async16(Vg + voff[r], &Vs[buf][vdst[r]]);
    };

    int qrow0 = qtA * 64 + w * 16;
    bf16x8 qf[4];
    auto loadQ = [&]() {
#pragma unroll
        for (int t = 0; t < 4; t++)
            qf[t] = *(const bf16x8*)&Qb[(long)(qrow0 + fr) * HDIM + t * 32 + fk];
    };
    loadQ();

    f32x4 o[8];
#pragma unroll
    for (int i = 0; i < 8; i++) o[i] = (f32x4){0.f, 0.f, 0.f, 0.f};
    float mrun = -1e30f, lrun = 0.f;

    const float scale = 0.08838834764831845f; // 1/sqrt(128)
    long obase = ((long)b * S_LEN) * DMODEL + (long)h * HDIM;
    auto flush = [&]() {
        float inv = 1.0f / lrun;
        long rowb = obase + (long)(qrow0 + fr) * DMODEL;
#pragma unroll
        for (int dt = 0; dt < 8; dt++) {
            ushort4 u;
            u.x = f2bf(o[dt][0] * inv); u.y = f2bf(o[dt][1] * inv);
            u.z = f2bf(o[dt][2] * inv); u.w = f2bf(o[dt][3] * inv);
            *(ushort4*)&ctx[rowb + dt * 16 + g * 4] = u;
        }
    };

    const int ntA = qtA + 1;
    const int ntot = 33; // ntA + (qtB+1) = 33 for every block

    stage(0, 0);
    __syncthreads();

    int cur = 0;
    for (int u = 0; u < ntot; ++u) {
        if (u + 1 < ntot) {
            int kvn = (u + 1 < ntA) ? (u + 1) : (u + 1 - ntA);
            stage(cur ^ 1, kvn * 64);
        }
        const int kv0 = ((u < ntA) ? u : (u - ntA)) * 64;
        if (u == ntA) { // phase switch A -> B
            flush();
            qrow0 = qtB * 64 + w * 16;
            loadQ();
#pragma unroll
            for (int i = 0; i < 8; i++) o[i] = (f32x4){0.f, 0.f, 0.f, 0.f};
            mrun = -1e30f; lrun = 0.f;
        }
        if (kv0 <= qrow0 + 15) {
            // ---- QK^T (swapped: A=K rows=kv, B=Q cols=q) ----
            f32x4 sf[4]; // [c]: kv = kv0+c*16+g*4+r, q = qrow0+fr
#pragma unroll
            for (int c = 0; c < 4; c++) sf[c] = (f32x4){0.f, 0.f, 0.f, 0.f};
            __builtin_amdgcn_s_setprio(1);
#pragma unroll
            for (int c = 0; c < 4; c++) {
                const int krow = c * 16 + fr;
#pragma unroll
                for (int tt = 0; tt < 4; tt++) {
                    bf16x8 kb = *(const bf16x8*)&Ks[cur][krow * 128 + (((tt * 4 + g) ^ (krow & 7)) * 8)];
                    sf[c] = __builtin_amdgcn_mfma_f32_16x16x32_bf16(kb, qf[tt], sf[c], 0, 0, 0);
                }
            }
            __builtin_amdgcn_s_setprio(0);
            // ---- scale + causal mask ----
            if (kv0 + 63 <= qrow0) {
#pragma unroll
                for (int c = 0; c < 4; c++)
#pragma unroll
                    for (int r = 0; r < 4; r++) sf[c][r] *= scale;
            } else {
                const int q = qrow0 + fr;
#pragma unroll
                for (int c = 0; c < 4; c++)
#pragma unroll
                    for (int r = 0; r < 4; r++) {
                        int kv = kv0 + c * 16 + g * 4 + r;
                        sf[c][r] = (kv <= q) ? sf[c][r] * scale : -1e30f;
                    }
            }
            // ---- online softmax (lane owns 16 kv of its q-row) ----
            {
                float vmax = -1e30f;
#pragma unroll
                for (int c = 0; c < 4; c++) {
                    float t0 = fmaxf(fmaxf(sf[c][0], sf[c][1]), fmaxf(sf[c][2], sf[c][3]));
                    vmax = fmaxf(vmax, t0);
                }
                vmax = fmaxf(vmax, __shfl_xor(vmax, 16));
                vmax = fmaxf(vmax, __shfl_xor(vmax, 32));
                if (!__all(vmax - mrun <= 8.f)) { // defer-max
                    float nm = fmaxf(mrun, vmax);
                    float alpha = __expf(mrun - nm);
                    mrun = nm;
                    lrun *= alpha;
#pragma unroll
                    for (int dt = 0; dt < 8; dt++) o[dt] *= alpha;
                }
                float rs = 0.f;
#pragma unroll
                for (int c = 0; c < 4; c++)
#pragma unroll
                    for (int r = 0; r < 4; r++) {
                        float pv = __expf(sf[c][r] - mrun);
                        sf[c][r] = pv;
                        rs += pv;
                    }
                rs += __shfl_xor(rs, 16);
                rs += __shfl_xor(rs, 32);
                lrun += rs;
            }
            // ---- P -> LDS [q=16][kv=64], b64-packed, XOR-swizzled ----
#pragma unroll
            for (int c = 0; c < 4; c++) {
                ushort4 u;
                u.x = f2bf(sf[c][0]); u.y = f2bf(sf[c][1]);
                u.z = f2bf(sf[c][2]); u.w = f2bf(sf[c][3]);
                *(ushort4*)&Pls[w][fr * 64 + ((c * 16 + g * 4) ^ ((fr & 7) << 3))] = u;
            }
            bf16x8 pa[2]; // B-frag: P[kv=hh*32+g*8+j][q=fr]
#pragma unroll
            for (int hh = 0; hh < 2; hh++)
                pa[hh] = *(const bf16x8*)&Pls[w][fr * 64 + ((hh * 32 + g * 8) ^ ((fr & 7) << 3))];
            // ---- PV: o = mfma(A=V^T rows=d, B=P cols=q) ----
            __builtin_amdgcn_s_setprio(1);
#pragma unroll
            for (int dt = 0; dt < 8; dt++) {
                const int vrow = dt * 16 + fr;
#pragma unroll
                for (int hh = 0; hh < 2; hh++) {
                    bf16x8 vb = *(const bf16x8*)&Vs[cur][vrow * 64 + (((hh * 4 + g) ^ (vrow & 7)) * 8)];
                    o[dt] = __builtin_amdgcn_mfma_f32_16x16x32_bf16(vb, pa[hh], o[dt], 0, 0, 0);
                }
            }
            __builtin_amdgcn_s_setprio(0);
        }
        __syncthreads();
        cur ^= 1;
    }
    flush();
}

extern "C" void kernel_launch(void* const* d_in, const int* in_sizes, int n_in,
                              void* d_out, int out_size, void* d_ws, size_t ws_size,
                              hipStream_t stream) {
    const float* hs = (const float*)d_in[0];
    const float* Wq = (const float*)d_in[1];
    const float* Wk = (const float*)d_in[2];
    const float* Wv = (const float*)d_in[3];
    const float* Wo = (const float*)d_in[4];
    float* out = (float*)d_out;

    size_t off = 0;
    char* wsb = (char*)d_ws;
    auto carve = [&](size_t bytes) { void* p = wsb + off; off += bytes; return p; };

    ushort_t* Xb   = (ushort_t*)carve((size_t)M_ROWS * DMODEL * 2);
    ushort_t* Wqb  = (ushort_t*)carve((size_t)DMODEL * DMODEL * 2); // Wq|Wk|Wv|Wo contiguous
    ushort_t* Wkb  = (ushort_t*)carve((size_t)DMODEL * DMODEL * 2);
    ushort_t* Wvb  = (ushort_t*)carve((size_t)DMODEL * DMODEL * 2);
    ushort_t* Wob  = (ushort_t*)carve((size_t)DMODEL * DMODEL * 2);
    ushort_t* Qb   = (ushort_t*)carve((size_t)BATCH * NH * S_LEN * HDIM * 2);
    ushort_t* Kb   = (ushort_t*)carve((size_t)BATCH * NH * S_LEN * HDIM * 2);
    ushort_t* Vtb  = (ushort_t*)carve((size_t)BATCH * NH * S_LEN * HDIM * 2);
    ushort_t* ctxb = (ushort_t*)carve((size_t)M_ROWS * DMODEL * 2);
    float* cosT    = (float*)carve((size_t)S_LEN * 64 * 4);
    float* sinT    = (float*)carve((size_t)S_LEN * 64 * 4);

    const int nX = M_ROWS * DMODEL;   // 8388608
    const int nW = DMODEL * DMODEL;   // 4194304

    cvt_bf16<<<(nX / 4) / 256, 256, 0, stream>>>(hs, Xb, nX / 4);
    cvt4_bf16<<<dim3((nW / 4) / 256, 4), 256, 0, stream>>>(Wq, Wk, Wv, Wo, Wqb, nW / 4);
    rope_tables<<<(S_LEN * 64) / 256, 256, 0, stream>>>(cosT, sinT);

    // Fused QKV projection: A = Xb [4096][2048], B = Wqb..Wvb as [6144][2048].
    // BM=256, BN=192 -> grid 16 x 32 = 512 blocks = exactly 2 rounds on 256 CUs.
    gemm256<0, 3><<<(M_ROWS / 256) * (3 * DMODEL / 192), 512, 0, stream>>>(
        Xb, Wqb, Qb, Kb, Vtb, 3 * DMODEL / 192, DMODEL);

    rope_inplace<<<(BATCH * NH * S_LEN * 64) / 256, 256, 0, stream>>>(Qb, Kb, cosT, sinT);

    attn_fwd_v4<<<512, 256, 0, stream>>>(Qb, Kb, Vtb, ctxb);

    // Output projection: BM=256, BN=128 -> grid 16 x 16 = 256 blocks = 1 full round.
    gemm256<2, 2><<<(M_ROWS / 256) * (DMODEL / 128), 512, 0, stream>>>(
        ctxb, Wob, out, nullptr, nullptr, DMODEL / 128, DMODEL);
}

// Round 9
// 250.469 us; speedup vs baseline: 2.5456x; 1.0530x over previous
//
#include <hip/hip_runtime.h>

typedef unsigned short ushort_t;
typedef __bf16 bf16x8 __attribute__((ext_vector_type(8)));
typedef float f32x4 __attribute__((ext_vector_type(4)));

#define S_LEN 2048
#define DMODEL 2048
#define NH 16
#define HDIM 128
#define BATCH 2
#define M_ROWS (BATCH * S_LEN) // 4096

__device__ __forceinline__ ushort_t f2bf(float f) {
    union { float f; unsigned u; } v; v.f = f;
    unsigned r = (v.u + 0x7fffu + ((v.u >> 16) & 1u)) >> 16;
    return (ushort_t)r;
}
__device__ __forceinline__ float bf2f(ushort_t u) {
    union { unsigned u; float f; } v; v.u = ((unsigned)u) << 16;
    return v.f;
}

__device__ __forceinline__ void async16(const void* g, void* l) {
    __builtin_amdgcn_global_load_lds(
        (const __attribute__((address_space(1))) void*)g,
        (__attribute__((address_space(3))) void*)l, 16, 0, 0);
}

// ---------------- fp32 -> bf16 (4 elems/thread) ----------------
__global__ void cvt_bf16(const float* __restrict__ in, ushort_t* __restrict__ out, int n4) {
    int i = blockIdx.x * blockDim.x + threadIdx.x;
    if (i >= n4) return;
    float4 f = ((const float4*)in)[i];
    ushort4 u;
    u.x = f2bf(f.x); u.y = f2bf(f.y); u.z = f2bf(f.z); u.w = f2bf(f.w);
    ((ushort4*)out)[i] = u;
}

// ---------------- fp32 -> bf16 for the 4 weight matrices in one launch ----------
__global__ void cvt4_bf16(const float* __restrict__ w0, const float* __restrict__ w1,
                          const float* __restrict__ w2, const float* __restrict__ w3,
                          ushort_t* __restrict__ out, int n4) {
    int i = blockIdx.x * blockDim.x + threadIdx.x;
    if (i >= n4) return;
    int which = blockIdx.y;
    const float* src = which == 0 ? w0 : which == 1 ? w1 : which == 2 ? w2 : w3;
    float4 f = ((const float4*)src)[i];
    ushort4 u;
    u.x = f2bf(f.x); u.y = f2bf(f.y); u.z = f2bf(f.z); u.w = f2bf(f.w);
    ((ushort4*)(out + (size_t)which * DMODEL * DMODEL))[i] = u;
}

// ---------------- RoPE tables [S][64] ----------------
__global__ void rope_tables(float* __restrict__ cosT, float* __restrict__ sinT) {
    int i = blockIdx.x * blockDim.x + threadIdx.x; // 2048*64
    int s = i >> 6, f = i & 63;
    float inv = powf(10000.0f, -(float)(2 * f) / 128.0f);
    float ang = (float)s * inv;
    cosT[i] = cosf(ang);
    sinT[i] = sinf(ang);
}

// ---------------- RoPE in-place on Q and K ([BH][S][HD] bf16) ----------------
__global__ void rope_inplace(ushort_t* __restrict__ Q, ushort_t* __restrict__ K,
                             const float* __restrict__ cosT, const float* __restrict__ sinT) {
    long i = (long)blockIdx.x * blockDim.x + threadIdx.x; // 32*2048*64
    int f = (int)(i & 63);
    long t = i >> 6;
    int s = (int)(t & (S_LEN - 1));
    int bh = (int)(t >> 11);
    long base = ((long)bh * S_LEN + s) * HDIM;
    float c = cosT[s * 64 + f], sn = sinT[s * 64 + f];
    float a0 = bf2f(Q[base + f]), a1 = bf2f(Q[base + 64 + f]);
    Q[base + f]      = f2bf(a0 * c - a1 * sn);
    Q[base + 64 + f] = f2bf(a1 * c + a0 * sn);
    float b0 = bf2f(K[base + f]), b1 = bf2f(K[base + 64 + f]);
    K[base + f]      = f2bf(b0 * c - b1 * sn);
    K[base + 64 + f] = f2bf(b1 * c + b0 * sn);
}

// ====== gemm128: BM=128, BN=NF*64, BK=64, 256 threads (4 waves 1x4) ======
// LDS = 32 + 16*NF KB -> EXACTLY 2 blocks/CU (NF=3: 80KB, NF=2: 64KB).
// Occupancy-decoupled overlap (R8 lesson): two independent co-resident blocks sit
// at different pipeline phases, so one block's ds_read burst overlaps the other's
// MFMA cluster (m114 mechanism). Same 3-bit XOR swizzle (128-B rows), counted-vmcnt
// 2-deep staging, single-region reads->MFMA body, setprio on MFMA cluster.
// EPI 0: fused [Q|K|V] cols (N=6144): Q/K scatter [B,H,S,HD], V -> [B,H,HD,S].
// EPI 2: fp32 row-major [M][2048] to d_out.
template <int EPI, int NF>
__global__ __launch_bounds__(256) void gemm128(
    const ushort_t* __restrict__ A, const ushort_t* __restrict__ Bm,
    void* __restrict__ C0, void* __restrict__ C1, void* __restrict__ C2,
    int NB, int K) {
    __shared__ __align__(16) ushort_t As[2][128 * 64];
    __shared__ __align__(16) ushort_t Bs[2][NF * 64 * 64];
    const int tid = threadIdx.x;
    const int lane = tid & 63;
    const int w = tid >> 6;                 // 0..3 = n-wave
    const int fr = lane & 15, g = lane >> 4;
    const int WN = NF * 16;
    const int BN = NF * 64;
    // XCD c owns B col-blocks [c*cpx, (c+1)*cpx); iterate row-blocks within.
    const int cpx = NB >> 3;
    const int xcd = blockIdx.x & 7;
    const int local = blockIdx.x >> 3;
    const int brow = (local / cpx) * 128;
    const int bcol = (xcd * cpx + local % cpx) * BN;

    // staging: linear LDS dest, involutive pre-swizzled global source
    int aRow[4], aK[4], bRow[2 * NF], bK[2 * NF];
#pragma unroll
    for (int q = 0; q < 4; q++) {
        int d = (q * 256 + tid) * 16;
        int row = d >> 7;
        int s = d ^ ((row & 7) << 4);
        aRow[q] = row; aK[q] = (s & 127) >> 1;
    }
#pragma unroll
    for (int q = 0; q < 2 * NF; q++) {
        int d = (q * 256 + tid) * 16;
        int row = d >> 7;
        int s = d ^ ((row & 7) << 4);
        bRow[q] = row; bK[q] = (s & 127) >> 1;
    }

    f32x4 acc[8][NF];
#pragma unroll
    for (int m = 0; m < 8; m++)
#pragma unroll
        for (int n = 0; n < NF; n++) acc[m][n] = (f32x4){0.f, 0.f, 0.f, 0.f};

    auto stage = [&](int buf, int k0) {
#pragma unroll
        for (int q = 0; q < 4; q++)
            async16(&A[(long)(brow + aRow[q]) * K + k0 + aK[q]], &As[buf][(q * 256 + tid) * 8]);
#pragma unroll
        for (int q = 0; q < 2 * NF; q++)
            async16(&Bm[(long)(bcol + bRow[q]) * K + k0 + bK[q]], &Bs[buf][(q * 256 + tid) * 8]);
    };
    auto rdA = [&](int buf, int m, int ks) -> bf16x8 {
        int row = m * 16 + fr;
        int cb = (ks * 64 + g * 16) ^ ((row & 7) << 4);
        return *(const bf16x8*)((const char*)&As[buf][0] + row * 128 + cb);
    };
    auto rdB = [&](int buf, int n, int ks) -> bf16x8 {
        int row = w * WN + n * 16 + fr;
        int cb = (ks * 64 + g * 16) ^ ((row & 7) << 4);
        return *(const bf16x8*)((const char*)&Bs[buf][0] + row * 128 + cb);
    };

    const int NT = K / 64;
    stage(0, 0);
    stage(1, 64);

    for (int kt = 0; kt < NT; ++kt) {
        const int cur = kt & 1;
        if (kt + 1 < NT) {
            if constexpr (NF == 2)      asm volatile("s_waitcnt vmcnt(8)" ::: "memory");
            else                        asm volatile("s_waitcnt vmcnt(10)" ::: "memory");
        } else {
            asm volatile("s_waitcnt vmcnt(0)" ::: "memory");
        }
        __builtin_amdgcn_sched_barrier(0);
        __builtin_amdgcn_s_barrier();
        __builtin_amdgcn_sched_barrier(0);

        // ---- issue fragment reads: B first, then A in consumption order ----
        bf16x8 bfv[NF][2], af[8][2];
#pragma unroll
        for (int n = 0; n < NF; n++)
#pragma unroll
            for (int ks = 0; ks < 2; ks++) bfv[n][ks] = rdB(cur, n, ks);
#pragma unroll
        for (int m = 0; m < 8; m++)
#pragma unroll
            for (int ks = 0; ks < 2; ks++) af[m][ks] = rdA(cur, m, ks);
        // ---- single MFMA block, m-major ----
        __builtin_amdgcn_s_setprio(1);
#pragma unroll
        for (int m = 0; m < 8; m++)
#pragma unroll
            for (int n = 0; n < NF; n++)
#pragma unroll
                for (int ks = 0; ks < 2; ks++)
                    acc[m][n] = __builtin_amdgcn_mfma_f32_16x16x32_bf16(af[m][ks], bfv[n][ks], acc[m][n], 0, 0, 0);
        __builtin_amdgcn_s_setprio(0);

        __builtin_amdgcn_s_barrier();   // all waves done reading buf cur
        __builtin_amdgcn_sched_barrier(0);
        if (kt + 2 < NT) stage(cur, (kt + 2) * 64);
    }

    if constexpr (EPI == 0) {
#pragma unroll
        for (int n = 0; n < NF; n++) {
            int c2abs = bcol + w * WN + n * 16 + fr;    // [0, 6144)
            int proj = c2abs >> 11;                     // 16-col frag never straddles
            int c2 = c2abs & 2047;
            int h = c2 >> 7, hd = c2 & 127;
            if (proj < 2) {
                ushort_t* dst = (ushort_t*)(proj == 0 ? C0 : C1);
#pragma unroll
                for (int m = 0; m < 8; m++)
#pragma unroll
                    for (int r = 0; r < 4; r++) {
                        int row = brow + m * 16 + g * 4 + r;
                        int b = row >> 11, s = row & (S_LEN - 1);
                        dst[(((long)(b * NH + h) * S_LEN) + s) * HDIM + hd] = f2bf(acc[m][n][r]);
                    }
            } else {
                ushort_t* dst = (ushort_t*)C2;
#pragma unroll
                for (int m = 0; m < 8; m++) {
                    int row0 = brow + m * 16 + g * 4;
                    int b = row0 >> 11, s0 = row0 & (S_LEN - 1);
                    ushort4 u;
                    u.x = f2bf(acc[m][n][0]); u.y = f2bf(acc[m][n][1]);
                    u.z = f2bf(acc[m][n][2]); u.w = f2bf(acc[m][n][3]);
                    *(ushort4*)&dst[(((long)(b * NH + h) * HDIM) + hd) * S_LEN + s0] = u;
                }
            }
        }
    } else {
        float* dst = (float*)C0;
#pragma unroll
        for (int m = 0; m < 8; m++)
#pragma unroll
            for (int n = 0; n < NF; n++) {
                int col = bcol + w * WN + n * 16 + fr;
#pragma unroll
                for (int r = 0; r < 4; r++) {
                    int row = brow + m * 16 + g * 4 + r;
                    dst[(long)row * DMODEL + col] = acc[m][n][r];
                }
            }
    }
}

// ---------------- Flash attention v4: uniform work pairing ----------
__global__ __launch_bounds__(256) void attn_fwd_v4(
    const ushort_t* __restrict__ Q, const ushort_t* __restrict__ K,
    const ushort_t* __restrict__ Vt, ushort_t* __restrict__ ctx) {
    __shared__ __align__(16) ushort_t Ks[2][64 * 128];
    __shared__ __align__(16) ushort_t Vs[2][128 * 64];
    __shared__ __align__(16) ushort_t Pls[4][16 * 64];

    const int tid = threadIdx.x;
    const int lane = tid & 63;
    const int w = tid >> 6;
    const int g = lane >> 4;
    const int fr = lane & 15;
    const int fk = g * 8;

    const int bid = blockIdx.x;              // 512 blocks
    const int xcd = bid & 7;
    const int t6 = bid >> 3;                 // 0..63
    const int bh = xcd + 8 * (t6 & 3);       // 4 heads per XCD
    const int p = t6 >> 2;                   // 0..15 pair index
    const int qtA = p, qtB = 31 - p;
    const int b = bh >> 4, h = bh & 15;

    const ushort_t* Qb = Q + (long)bh * S_LEN * HDIM;
    const ushort_t* Kb = K + (long)bh * S_LEN * HDIM;
    const ushort_t* Vb = Vt + (long)bh * HDIM * S_LEN;

    int koff[4], voff[4], kdst[4], vdst[4];
#pragma unroll
    for (int r = 0; r < 4; r++) {
        int ci = r * 256 + tid;
        int krow = ci >> 4, kwc = ci & 15;
        koff[r] = krow * HDIM + ((kwc ^ (krow & 7)) * 8);
        kdst[r] = ci * 8;
        int vrow = ci >> 3, vwc = ci & 7;
        voff[r] = vrow * S_LEN + ((vwc ^ (vrow & 7)) * 8);
        vdst[r] = ci * 8;
    }
    auto stage = [&](int buf, int kv0) {
        const ushort_t* Kg = Kb + (long)kv0 * HDIM;
        const ushort_t* Vg = Vb + kv0;
#pragma unroll
        for (int r = 0; r < 4; r++) async16(Kg + koff[r], &Ks[buf][kdst[r]]);
#pragma unroll
        for (int r = 0; r < 4; r++) async16(Vg + voff[r], &Vs[buf][vdst[r]]);
    };

    int qrow0 = qtA * 64 + w * 16;
    bf16x8 qf[4];
    auto loadQ = [&]() {
#pragma unroll
        for (int t = 0; t < 4; t++)
            qf[t] = *(const bf16x8*)&Qb[(long)(qrow0 + fr) * HDIM + t * 32 + fk];
    };
    loadQ();

    f32x4 o[8];
#pragma unroll
    for (int i = 0; i < 8; i++) o[i] = (f32x4){0.f, 0.f, 0.f, 0.f};
    float mrun = -1e30f, lrun = 0.f;

    const float scale = 0.08838834764831845f; // 1/sqrt(128)
    long obase = ((long)b * S_LEN) * DMODEL + (long)h * HDIM;
    auto flush = [&]() {
        float inv = 1.0f / lrun;
        long rowb = obase + (long)(qrow0 + fr) * DMODEL;
#pragma unroll
        for (int dt = 0; dt < 8; dt++) {
            ushort4 u;
            u.x = f2bf(o[dt][0] * inv); u.y = f2bf(o[dt][1] * inv);
            u.z = f2bf(o[dt][2] * inv); u.w = f2bf(o[dt][3] * inv);
            *(ushort4*)&ctx[rowb + dt * 16 + g * 4] = u;
        }
    };

    const int ntA = qtA + 1;
    const int ntot = 33; // ntA + (qtB+1) = 33 for every block

    stage(0, 0);
    __syncthreads();

    int cur = 0;
    for (int u = 0; u < ntot; ++u) {
        if (u + 1 < ntot) {
            int kvn = (u + 1 < ntA) ? (u + 1) : (u + 1 - ntA);
            stage(cur ^ 1, kvn * 64);
        }
        const int kv0 = ((u < ntA) ? u : (u - ntA)) * 64;
        if (u == ntA) { // phase switch A -> B
            flush();
            qrow0 = qtB * 64 + w * 16;
            loadQ();
#pragma unroll
            for (int i = 0; i < 8; i++) o[i] = (f32x4){0.f, 0.f, 0.f, 0.f};
            mrun = -1e30f; lrun = 0.f;
        }
        if (kv0 <= qrow0 + 15) {
            // ---- QK^T (swapped: A=K rows=kv, B=Q cols=q) ----
            f32x4 sf[4]; // [c]: kv = kv0+c*16+g*4+r, q = qrow0+fr
#pragma unroll
            for (int c = 0; c < 4; c++) sf[c] = (f32x4){0.f, 0.f, 0.f, 0.f};
            __builtin_amdgcn_s_setprio(1);
#pragma unroll
            for (int c = 0; c < 4; c++) {
                const int krow = c * 16 + fr;
#pragma unroll
                for (int tt = 0; tt < 4; tt++) {
                    bf16x8 kb = *(const bf16x8*)&Ks[cur][krow * 128 + (((tt * 4 + g) ^ (krow & 7)) * 8)];
                    sf[c] = __builtin_amdgcn_mfma_f32_16x16x32_bf16(kb, qf[tt], sf[c], 0, 0, 0);
                }
            }
            __builtin_amdgcn_s_setprio(0);
            // ---- scale + causal mask ----
            if (kv0 + 63 <= qrow0) {
#pragma unroll
                for (int c = 0; c < 4; c++)
#pragma unroll
                    for (int r = 0; r < 4; r++) sf[c][r] *= scale;
            } else {
                const int q = qrow0 + fr;
#pragma unroll
                for (int c = 0; c < 4; c++)
#pragma unroll
                    for (int r = 0; r < 4; r++) {
                        int kv = kv0 + c * 16 + g * 4 + r;
                        sf[c][r] = (kv <= q) ? sf[c][r] * scale : -1e30f;
                    }
            }
            // ---- online softmax (lane owns 16 kv of its q-row) ----
            {
                float vmax = -1e30f;
#pragma unroll
                for (int c = 0; c < 4; c++) {
                    float t0 = fmaxf(fmaxf(sf[c][0], sf[c][1]), fmaxf(sf[c][2], sf[c][3]));
                    vmax = fmaxf(vmax, t0);
                }
                vmax = fmaxf(vmax, __shfl_xor(vmax, 16));
                vmax = fmaxf(vmax, __shfl_xor(vmax, 32));
                if (!__all(vmax - mrun <= 8.f)) { // defer-max
                    float nm = fmaxf(mrun, vmax);
                    float alpha = __expf(mrun - nm);
                    mrun = nm;
                    lrun *= alpha;
#pragma unroll
                    for (int dt = 0; dt < 8; dt++) o[dt] *= alpha;
                }
                float rs = 0.f;
#pragma unroll
                for (int c = 0; c < 4; c++)
#pragma unroll
                    for (int r = 0; r < 4; r++) {
                        float pv = __expf(sf[c][r] - mrun);
                        sf[c][r] = pv;
                        rs += pv;
                    }
                rs += __shfl_xor(rs, 16);
                rs += __shfl_xor(rs, 32);
                lrun += rs;
            }
            // ---- P -> LDS [q=16][kv=64], b64-packed, XOR-swizzled ----
#pragma unroll
            for (int c = 0; c < 4; c++) {
                ushort4 u;
                u.x = f2bf(sf[c][0]); u.y = f2bf(sf[c][1]);
                u.z = f2bf(sf[c][2]); u.w = f2bf(sf[c][3]);
                *(ushort4*)&Pls[w][fr * 64 + ((c * 16 + g * 4) ^ ((fr & 7) << 3))] = u;
            }
            bf16x8 pa[2]; // B-frag: P[kv=hh*32+g*8+j][q=fr]
#pragma unroll
            for (int hh = 0; hh < 2; hh++)
                pa[hh] = *(const bf16x8*)&Pls[w][fr * 64 + ((hh * 32 + g * 8) ^ ((fr & 7) << 3))];
            // ---- PV: o = mfma(A=V^T rows=d, B=P cols=q) ----
            __builtin_amdgcn_s_setprio(1);
#pragma unroll
            for (int dt = 0; dt < 8; dt++) {
                const int vrow = dt * 16 + fr;
#pragma unroll
                for (int hh = 0; hh < 2; hh++) {
                    bf16x8 vb = *(const bf16x8*)&Vs[cur][vrow * 64 + (((hh * 4 + g) ^ (vrow & 7)) * 8)];
                    o[dt] = __builtin_amdgcn_mfma_f32_16x16x32_bf16(vb, pa[hh], o[dt], 0, 0, 0);
                }
            }
            __builtin_amdgcn_s_setprio(0);
        }
        __syncthreads();
        cur ^= 1;
    }
    flush();
}

extern "C" void kernel_launch(void* const* d_in, const int* in_sizes, int n_in,
                              void* d_out, int out_size, void* d_ws, size_t ws_size,
                              hipStream_t stream) {
    const float* hs = (const float*)d_in[0];
    const float* Wq = (const float*)d_in[1];
    const float* Wk = (const float*)d_in[2];
    const float* Wv = (const float*)d_in[3];
    const float* Wo = (const float*)d_in[4];
    float* out = (float*)d_out;

    size_t off = 0;
    char* wsb = (char*)d_ws;
    auto carve = [&](size_t bytes) { void* p = wsb + off; off += bytes; return p; };

    ushort_t* Xb   = (ushort_t*)carve((size_t)M_ROWS * DMODEL * 2);
    ushort_t* Wqb  = (ushort_t*)carve((size_t)DMODEL * DMODEL * 2); // Wq|Wk|Wv|Wo contiguous
    ushort_t* Wkb  = (ushort_t*)carve((size_t)DMODEL * DMODEL * 2);
    ushort_t* Wvb  = (ushort_t*)carve((size_t)DMODEL * DMODEL * 2);
    ushort_t* Wob  = (ushort_t*)carve((size_t)DMODEL * DMODEL * 2);
    ushort_t* Qb   = (ushort_t*)carve((size_t)BATCH * NH * S_LEN * HDIM * 2);
    ushort_t* Kb   = (ushort_t*)carve((size_t)BATCH * NH * S_LEN * HDIM * 2);
    ushort_t* Vtb  = (ushort_t*)carve((size_t)BATCH * NH * S_LEN * HDIM * 2);
    ushort_t* ctxb = (ushort_t*)carve((size_t)M_ROWS * DMODEL * 2);
    float* cosT    = (float*)carve((size_t)S_LEN * 64 * 4);
    float* sinT    = (float*)carve((size_t)S_LEN * 64 * 4);

    const int nX = M_ROWS * DMODEL;   // 8388608
    const int nW = DMODEL * DMODEL;   // 4194304

    cvt_bf16<<<(nX / 4) / 256, 256, 0, stream>>>(hs, Xb, nX / 4);
    cvt4_bf16<<<dim3((nW / 4) / 256, 4), 256, 0, stream>>>(Wq, Wk, Wv, Wo, Wqb, nW / 4);
    rope_tables<<<(S_LEN * 64) / 256, 256, 0, stream>>>(cosT, sinT);

    // Fused QKV projection: A = Xb [4096][2048], B = Wqb..Wvb as [6144][2048].
    // BM=128, BN=192 -> grid 32 x 32 = 1024 blocks; 2 blocks/CU -> 2 pair-rounds.
    gemm128<0, 3><<<(M_ROWS / 128) * (3 * DMODEL / 192), 256, 0, stream>>>(
        Xb, Wqb, Qb, Kb, Vtb, 3 * DMODEL / 192, DMODEL);

    rope_inplace<<<(BATCH * NH * S_LEN * 64) / 256, 256, 0, stream>>>(Qb, Kb, cosT, sinT);

    attn_fwd_v4<<<512, 256, 0, stream>>>(Qb, Kb, Vtb, ctxb);

    // Output projection: BM=128, BN=128 -> grid 32 x 16 = 512 blocks = 1 pair-round.
    gemm128<2, 2><<<(M_ROWS / 128) * (DMODEL / 128), 256, 0, stream>>>(
        ctxb, Wob, out, nullptr, nullptr, DMODEL / 128, DMODEL);
}